// Round 7
// baseline (616.950 us; speedup 1.0000x reference)
//
#include <hip/hip_runtime.h>
#include <hip/hip_bf16.h>

typedef __hip_bfloat16 bf16;

#define D 128
#define NLEV 5
#define TE 8   // edges per tile (4 waves: (struct|func) x K-half)
#define TN 16  // nodes per tile (2 waves: row halves of 8)

// gate code -> t (enumerate index in CODES=[3,2,5,1,4]); index 0 unused
__constant__ int TMAP[6] = { -1, 3, 1, 0, 4, 2 };
// gate code -> func-aggregator index (FIDX={3:0,5:1,1:2,4:3}); codes 0,2 unused
__constant__ int FMAP[6] = { -1, 2, -1, 0, 3, 1 };

// dtype flag: 1 = float tensors stored as bf16, 0 = stored as float32
__device__ int g_flag;

__device__ __forceinline__ float sigm(float x) { return 1.0f / (1.0f + __expf(-x)); }

// wave-uniform register broadcast (VALU, no LDS pipe)
__device__ __forceinline__ float rlane(float v, int ln) {
    return __int_as_float(__builtin_amdgcn_readlane(__float_as_int(v), ln));
}

template <int ISB>
__device__ __forceinline__ float ld(const void* p, size_t i) {
    if (ISB) return __bfloat162float(((const bf16*)p)[i]);
    return ((const float*)p)[i];
}

// load two adjacent elements (i must be even)
template <int ISB>
__device__ __forceinline__ float2 ld2(const void* p, size_t i) {
    if (ISB) {
        __hip_bfloat162 v = *(const __hip_bfloat162*)((const bf16*)p + i);
        return make_float2(__bfloat162float(v.x), __bfloat162float(v.y));
    }
    return *(const float2*)((const float*)p + i);
}

// ---- dtype sniffer ----
__global__ void detect_dtype(const void* hs_init) {
    int t = threadIdx.x;
    float x = __bfloat162float(((const bf16*)hs_init)[2 * t]);
    float ax = fabsf(x);
    bool sane = (x == 0.0f) || (ax > 1e-4f && ax < 64.0f);
    unsigned long long m = __ballot(sane);
    if (t == 0) g_flag = (__popcll(m) >= 32) ? 1 : 0;
}

// ---- init: hs = PI ? hs_init : 0 ; hf = 0 ----
__global__ void init_state(const void* __restrict__ hs_init,
                           const int* __restrict__ gate,
                           float* __restrict__ hs, float* __restrict__ hf) {
    int v = blockIdx.x;
    int j = threadIdx.x;
    float val = 0.0f;
    if (gate[v] == 0) {
        size_t idx = (size_t)v * D + j;
        val = g_flag ? ld<1>(hs_init, idx) : ld<0>(hs_init, idx);
    }
    hs[(size_t)v * D + j] = val;
    hf[(size_t)v * D + j] = 0.0f;
}

// ================= bucketing: (level-1)*5 + t, levels 1..4 =================
__global__ void count_bins(const int* __restrict__ dstA, const int* __restrict__ gate,
                           const int* __restrict__ lev, int E, int N,
                           int* __restrict__ ecnt, int* __restrict__ ncnt) {
    __shared__ int lc[40];
    int tid = threadIdx.x;
    if (tid < 40) lc[tid] = 0;
    __syncthreads();
    int i = blockIdx.x * blockDim.x + tid;
    if (i < E) {
        int d = dstA[i]; int l = lev[d];
        if (l >= 1 && l < NLEV) atomicAdd(&lc[(l - 1) * 5 + TMAP[gate[d]]], 1);
    }
    if (i < N) {
        int l = lev[i];
        if (l >= 1 && l < NLEV && gate[i] >= 1) atomicAdd(&lc[20 + (l - 1) * 5 + TMAP[gate[i]]], 1);
    }
    __syncthreads();
    if (tid < 20 && lc[tid]) atomicAdd(&ecnt[tid], lc[tid]);
    if (tid >= 20 && tid < 40 && lc[tid]) atomicAdd(&ncnt[tid - 20], lc[tid]);
}

__global__ void scan_offsets(const int* __restrict__ ecnt, const int* __restrict__ ncnt,
                             int* __restrict__ eoff, int* __restrict__ noff) {
    if (threadIdx.x == 0 && blockIdx.x == 0) {
        int o = 0;
        for (int b = 0; b < 20; ++b) { eoff[b] = o; o += ((ecnt[b] + TE - 1) / TE) * TE; }
        eoff[20] = o;
        o = 0;
        for (int b = 0; b < 20; ++b) { noff[b] = o; o += ((ncnt[b] + TN - 1) / TN) * TN; }
        noff[20] = o;
    }
}

__global__ void fill_bins(const int* __restrict__ dstA, const int* __restrict__ gate,
                          const int* __restrict__ lev, int E, int N,
                          const int* __restrict__ eoff, const int* __restrict__ noff,
                          int* __restrict__ ecur, int* __restrict__ ncur,
                          int* __restrict__ elist, int* __restrict__ nlist) {
    __shared__ int ec[20], nc[20], eb[20], nb[20];
    int tid = threadIdx.x;
    if (tid < 20) { ec[tid] = 0; nc[tid] = 0; }
    __syncthreads();
    int i = blockIdx.x * blockDim.x + tid;
    int be = -1, re = 0, bn = -1, rn = 0;
    if (i < E) {
        int d = dstA[i]; int l = lev[d];
        if (l >= 1 && l < NLEV) { be = (l - 1) * 5 + TMAP[gate[d]]; re = atomicAdd(&ec[be], 1); }
    }
    if (i < N) {
        int l = lev[i];
        if (l >= 1 && l < NLEV && gate[i] >= 1) { bn = (l - 1) * 5 + TMAP[gate[i]]; rn = atomicAdd(&nc[bn], 1); }
    }
    __syncthreads();
    if (tid < 20) {
        eb[tid] = ec[tid] ? atomicAdd(&ecur[tid], ec[tid]) : 0;
        nb[tid] = nc[tid] ? atomicAdd(&ncur[tid], nc[tid]) : 0;
    }
    __syncthreads();
    if (be >= 0) elist[eoff[be] + eb[be] + re] = i;
    if (bn >= 0) nlist[noff[bn] + nb[bn] + rn] = i;
}

// ================= register-broadcast GEMM slices =================
// Output: lane owns cols (c0, c0+1). Accumulate into out[R][2].
// mmA: X held 1-per-lane: x[r] = X[r][lane] (K=64 window), W rows [0,64) of wofs
template <int ISB, int R>
__device__ __forceinline__ void mmA(
    const float (&x)[R],
    const void* __restrict__ W, size_t wofs, int wstride,
    int c0, float (&out)[R][2]) {
#pragma unroll 4
    for (int k = 0; k < 64; k += 2) {
        float2 w0 = ld2<ISB>(W, wofs + (size_t)k * wstride + c0);
        float2 w1 = ld2<ISB>(W, wofs + (size_t)(k + 1) * wstride + c0);
#pragma unroll
        for (int r = 0; r < R; ++r) {
            float xa = rlane(x[r], k);
            float xb = rlane(x[r], k + 1);
            out[r][0] = fmaf(xb, w1.x, fmaf(xa, w0.x, out[r][0]));
            out[r][1] = fmaf(xb, w1.y, fmaf(xa, w0.y, out[r][1]));
        }
    }
}

// mmB: X held 2-per-lane: x0[r]=X[r][2*lane], x1[r]=X[r][2*lane+1].
// Processes MC pairs starting at pair index mstart (k rows 2m, 2m+1).
template <int ISB, int MC, int R>
__device__ __forceinline__ void mmB(
    const float (&x0)[R], const float (&x1)[R],
    const void* __restrict__ W, size_t wofs, int wstride,
    int mstart, int c0, float (&out)[R][2]) {
#pragma unroll 4
    for (int mm = 0; mm < MC; ++mm) {
        int m = mstart + mm;
        float2 w0 = ld2<ISB>(W, wofs + (size_t)(2 * m) * wstride + c0);
        float2 w1 = ld2<ISB>(W, wofs + (size_t)(2 * m + 1) * wstride + c0);
#pragma unroll
        for (int r = 0; r < R; ++r) {
            float xa = rlane(x0[r], m);
            float xb = rlane(x1[r], m);
            out[r][0] = fmaf(xb, w1.x, fmaf(xa, w0.x, out[r][0]));
            out[r][1] = fmaf(xb, w1.y, fmaf(xa, w0.y, out[r][1]));
        }
    }
}

// ===== edge tiles: 4 waves = (struct|func) x (K-half); LDS only for L1 partials =====
template <int ISB>
__device__ void edge_tiles_body(
    const float* __restrict__ hs, const float* __restrict__ hf,
    const void* __restrict__ Ws1, const void* __restrict__ bs1,
    const void* __restrict__ Ws2, const void* __restrict__ bs2,
    const void* __restrict__ Wf1, const void* __restrict__ bf1,
    const void* __restrict__ Wf2, const void* __restrict__ bf2,
    const void* __restrict__ Wnf1, const void* __restrict__ bnf1,
    const void* __restrict__ Wnf2, const void* __restrict__ bnf2,
    const int* __restrict__ srcA, const int* __restrict__ dstA,
    const int* __restrict__ gate,
    const int* __restrict__ eoff, const int* __restrict__ elist,
    float* __restrict__ agg_s, float* __restrict__ agg_f, int level,
    int* se, int* de, float* part) {
    int lo = eoff[(level - 1) * 5];
    int hi = eoff[(level - 1) * 5 + 5];
    int base = lo + blockIdx.x * TE;
    if (base >= hi) return;
    int tid = threadIdx.x;
    int wv = tid >> 6;
    int pass = wv >> 1;        // 0: structural, 1: functional
    int h = wv & 1;            // K-half
    int l = tid & 63;
    int c0 = 2 * l;

    int e0 = elist[base];
    int c = gate[dstA[e0]];    // uniform over tile (buckets padded to TE)
    int t = TMAP[c];
    int fi = FMAP[c];          // -1 for c==2, unused then

    if (tid < TE) {
        int e = elist[base + tid];
        se[tid] = (e < 0) ? -1 : srcA[e];
        de[tid] = (e < 0) ? -1 : dstA[e];
    }
    __syncthreads();

    float acc[TE][2];
#pragma unroll
    for (int r = 0; r < TE; ++r) { acc[r][0] = 0.f; acc[r][1] = 0.f; }

    // ---- layer 1 partial (this wave's K-chunk) ----
    if (pass == 0) {
        float xa[TE];
#pragma unroll
        for (int r = 0; r < TE; ++r) {
            int s = se[r];
            xa[r] = (s >= 0) ? hs[(size_t)s * D + 64 * h + l] : 0.f;
        }
        mmA<ISB, TE>(xa, Ws1, (size_t)t * D * D + (size_t)(64 * h) * D, D, c0, acc);
    } else if (c == 2) {
        float xa[TE];
#pragma unroll
        for (int r = 0; r < TE; ++r) {
            int s = se[r];
            xa[r] = (s >= 0) ? hf[(size_t)s * D + 64 * h + l] : 0.f;
        }
        mmA<ISB, TE>(xa, Wnf1, (size_t)(64 * h) * D, D, c0, acc);
    } else {
        // func non-NOT: K=256 over [hs;hf]; half h covers one 128-row block
        float x0[TE], x1[TE];
        const float* src = h ? hf : hs;
#pragma unroll
        for (int r = 0; r < TE; ++r) {
            int s = se[r];
            float2 v = (s >= 0) ? *(const float2*)&src[(size_t)s * D + c0]
                                : make_float2(0.f, 0.f);
            x0[r] = v.x; x1[r] = v.y;
        }
        mmB<ISB, 64, TE>(x0, x1, Wf1,
                         (size_t)fi * 2 * D * D + (size_t)h * 128 * D, D, 0, c0, acc);
    }

    // ---- stash partials, combine across K-halves ----
#pragma unroll
    for (int r = 0; r < TE; ++r)
        *(float2*)&part[((size_t)(pass * 2 + h) * TE + r) * D + c0] =
            make_float2(acc[r][0], acc[r][1]);
    __syncthreads();

    float2 b1;
    if (pass == 0) b1 = ld2<ISB>(bs1, (size_t)t * D + c0);
    else if (c == 2) b1 = ld2<ISB>(bnf1, c0);
    else b1 = ld2<ISB>(bf1, (size_t)fi * D + c0);

    float h0r[TE], h1r[TE];
#pragma unroll
    for (int r = 0; r < TE; ++r) {
        float2 pa = *(const float2*)&part[((size_t)(pass * 2 + 0) * TE + r) * D + c0];
        float2 pb = *(const float2*)&part[((size_t)(pass * 2 + 1) * TE + r) * D + c0];
        h0r[r] = fmaxf(pa.x + pb.x + b1.x, 0.f);
        h1r[r] = fmaxf(pa.y + pb.y + b1.y, 0.f);
    }

    // ---- layer 2, K-split: this wave handles hidden k in [64h, 64h+64) ----
    if (h == 0) {
        float2 b2;
        if (pass == 0) b2 = ld2<ISB>(bs2, (size_t)t * D + c0);
        else if (c == 2) b2 = ld2<ISB>(bnf2, c0);
        else b2 = ld2<ISB>(bf2, (size_t)fi * D + c0);
#pragma unroll
        for (int r = 0; r < TE; ++r) { acc[r][0] = b2.x; acc[r][1] = b2.y; }
    } else {
#pragma unroll
        for (int r = 0; r < TE; ++r) { acc[r][0] = 0.f; acc[r][1] = 0.f; }
    }
    const void* W2 = (pass == 0) ? Ws2 : (c == 2 ? Wnf2 : Wf2);
    size_t wofs2 = (pass == 0) ? (size_t)t * D * D : (c == 2 ? 0 : (size_t)fi * D * D);
    mmB<ISB, 32, TE>(h0r, h1r, W2, wofs2, D, 32 * h, c0, acc);

    float* aggp = pass ? agg_f : agg_s;
#pragma unroll
    for (int r = 0; r < TE; ++r) {
        int d = de[r];
        if (d >= 0) {
            atomicAdd(&aggp[(size_t)d * D + c0], acc[r][0]);
            atomicAdd(&aggp[(size_t)d * D + c0 + 1], acc[r][1]);
        }
    }
}

__global__ __launch_bounds__(256) void edge_tiles(
    const float* hs, const float* hf,
    const void* Ws1, const void* bs1, const void* Ws2, const void* bs2,
    const void* Wf1, const void* bf1, const void* Wf2, const void* bf2,
    const void* Wnf1, const void* bnf1, const void* Wnf2, const void* bnf2,
    const int* srcA, const int* dstA, const int* gate,
    const int* eoff, const int* elist,
    float* agg_s, float* agg_f, int level) {
    __shared__ int se[TE], de[TE];
    __shared__ __align__(16) float part[4 * TE * D];
    if (g_flag)
        edge_tiles_body<1>(hs, hf, Ws1, bs1, Ws2, bs2, Wf1, bf1, Wf2, bf2,
                           Wnf1, bnf1, Wnf2, bnf2, srcA, dstA, gate, eoff, elist,
                           agg_s, agg_f, level, se, de, part);
    else
        edge_tiles_body<0>(hs, hf, Ws1, bs1, Ws2, bs2, Wf1, bf1, Wf2, bf2,
                           Wnf1, bnf1, Wnf2, bnf2, srcA, dstA, gate, eoff, elist,
                           agg_s, agg_f, level, se, de, part);
}

// ===== node GEMM: gi partials; blockIdx.y = p*3 + g; full K=128 per wave =====
template <int ISB>
__device__ void node_gemm_body(
    const float* __restrict__ agg_s, const float* __restrict__ agg_f,
    const void* __restrict__ Gs_wih, const void* __restrict__ Gf_wih,
    const int* __restrict__ gate,
    const int* __restrict__ noff, const int* __restrict__ nlist,
    float* __restrict__ gtmp, int level, int cap) {
    int lo = noff[(level - 1) * 5];
    int hi = noff[(level - 1) * 5 + 5];
    int base = lo + blockIdx.x * TN;
    if (base >= hi) return;
    int y = blockIdx.y;
    int p = y / 3, g = y % 3;
    int tid = threadIdx.x;
    int wv = tid >> 6;
    int r0 = wv * (TN / 2);
    int l = tid & 63;
    int c0 = 2 * l;
    int cw = g * 128 + c0;
    int t = TMAP[gate[nlist[base]]];

    const float* agg = p ? agg_f : agg_s;
    const void* wih = p ? Gf_wih : Gs_wih;

    float x0[TN / 2], x1[TN / 2];
#pragma unroll
    for (int r = 0; r < TN / 2; ++r) {
        int v = nlist[base + r0 + r];
        float2 a = (v >= 0) ? *(const float2*)&agg[(size_t)v * D + c0]
                            : make_float2(0.f, 0.f);
        x0[r] = a.x; x1[r] = a.y;
    }

    float acc[TN / 2][2];
#pragma unroll
    for (int r = 0; r < TN / 2; ++r) { acc[r][0] = 0.f; acc[r][1] = 0.f; }
    mmB<ISB, 64, TN / 2>(x0, x1, wih, (size_t)t * D * 3 * D, 3 * D, 0, cw, acc);

    size_t tb = ((size_t)p * cap + (base - lo)) * 384 + cw;
#pragma unroll
    for (int r = 0; r < TN / 2; ++r) {
        *(float2*)&gtmp[tb + (size_t)(r0 + r) * 384] = make_float2(acc[r][0], acc[r][1]);
    }
}

__global__ __launch_bounds__(128) void node_gemm(
    const float* agg_s, const float* agg_f,
    const void* Gs_wih, const void* Gf_wih,
    const int* gate, const int* noff, const int* nlist,
    float* gtmp, int level, int cap) {
    if (g_flag)
        node_gemm_body<1>(agg_s, agg_f, Gs_wih, Gf_wih, gate, noff, nlist, gtmp, level, cap);
    else
        node_gemm_body<0>(agg_s, agg_f, Gs_wih, Gf_wih, gate, noff, nlist, gtmp, level, cap);
}

// ===== node epilogue: biases + GRU nonlinearity =====
template <int ISB>
__device__ void node_epi_body(
    float* __restrict__ hs, float* __restrict__ hf,
    const float* __restrict__ gtmp,
    const void* __restrict__ Gs_bih, const void* __restrict__ Gs_bhh,
    const void* __restrict__ Gf_bih, const void* __restrict__ Gf_bhh,
    const int* __restrict__ gate,
    const int* __restrict__ noff, const int* __restrict__ nlist,
    int level, int cap) {
    int lo = noff[(level - 1) * 5];
    int hi = noff[(level - 1) * 5 + 5];
    int base = lo + blockIdx.x * TN;
    if (base >= hi) return;
    int j = threadIdx.x;  // 0..127
    int t = TMAP[gate[nlist[base]]];

#pragma unroll
    for (int p = 0; p < 2; ++p) {
        const void* bih = p ? Gf_bih : Gs_bih;
        const void* bhh = p ? Gf_bhh : Gs_bhh;
        float br = ld<ISB>(bih, (size_t)t * 384 + j);
        float bz = ld<ISB>(bih, (size_t)t * 384 + 128 + j);
        float bn = ld<ISB>(bih, (size_t)t * 384 + 256 + j);
        float hr = ld<ISB>(bhh, (size_t)t * 384 + j);
        float hz = ld<ISB>(bhh, (size_t)t * 384 + 128 + j);
        float hn = ld<ISB>(bhh, (size_t)t * 384 + 256 + j);
        float* hout = p ? hf : hs;
        const float* g0 = gtmp + (size_t)p * cap * 384;
#pragma unroll
        for (int r = 0; r < TN; ++r) {
            int v = nlist[base + r];
            if (v < 0) continue;
            size_t pos = (size_t)(base - lo + r) * 384;
            float gr = g0[pos + j];
            float gz = g0[pos + 128 + j];
            float gn = g0[pos + 256 + j];
            float rr = sigm(gr + br + hr);
            float z = sigm(gz + bz + hz);
            float n = tanhf(gn + bn + rr * hn);
            hout[(size_t)v * D + j] = (1.f - z) * n;
        }
    }
}

__global__ __launch_bounds__(128) void node_epi(
    float* hs, float* hf, const float* gtmp,
    const void* Gs_bih, const void* Gs_bhh,
    const void* Gf_bih, const void* Gf_bhh,
    const int* gate, const int* noff, const int* nlist, int level, int cap) {
    if (g_flag)
        node_epi_body<1>(hs, hf, gtmp, Gs_bih, Gs_bhh, Gf_bih, Gf_bhh,
                         gate, noff, nlist, level, cap);
    else
        node_epi_body<0>(hs, hf, gtmp, Gs_bih, Gs_bhh, Gf_bih, Gf_bhh,
                         gate, noff, nlist, level, cap);
}

// ---------------- writeout ----------------
__global__ void writeout(const float* __restrict__ hs, const float* __restrict__ hf,
                         void* __restrict__ out, int ND) {
    int i = blockIdx.x * blockDim.x + threadIdx.x;
    if (i >= ND) return;
    if (g_flag) {
        ((bf16*)out)[i] = __float2bfloat16(hs[i]);
        ((bf16*)out)[ND + i] = __float2bfloat16(hf[i]);
    } else {
        ((float*)out)[i] = hs[i];
        ((float*)out)[ND + i] = hf[i];
    }
}

extern "C" void kernel_launch(void* const* d_in, const int* in_sizes, int n_in,
                              void* d_out, int out_size, void* d_ws, size_t ws_size,
                              hipStream_t stream) {
    const void* hs_init = d_in[0];
    const void* Ws1 = d_in[1];
    const void* bs1 = d_in[2];
    const void* Ws2 = d_in[3];
    const void* bs2 = d_in[4];
    const void* Wf1 = d_in[5];
    const void* bf1 = d_in[6];
    const void* Wf2 = d_in[7];
    const void* bf2 = d_in[8];
    const void* Wnf1 = d_in[9];
    const void* bnf1 = d_in[10];
    const void* Wnf2 = d_in[11];
    const void* bnf2 = d_in[12];
    const void* Gs_wih = d_in[13];
    // d_in[14] = Gs_whh (unused: h==0 at GRU time)
    const void* Gs_bih = d_in[15];
    const void* Gs_bhh = d_in[16];
    const void* Gf_wih = d_in[17];
    // d_in[18] = Gf_whh (unused)
    const void* Gf_bih = d_in[19];
    const void* Gf_bhh = d_in[20];
    const int* edge_index = (const int*)d_in[21];
    const int* gate = (const int*)d_in[22];
    const int* lev = (const int*)d_in[23];

    int E = in_sizes[21] / 2;
    int N = in_sizes[22];
    int ND = N * D;
    // per-level node window bound: levels are ~N/NLEV nodes + bucket padding
    int cap = ((N / NLEV + 5 * TN + 64) + TN - 1) / TN * TN;

    float* hs = (float*)d_ws;
    float* hf = hs + ND;
    float* agg_s = hf + ND;
    float* agg_f = agg_s + ND;
    float* gtmp = agg_f + ND;                  // 2 * cap * 384 floats
    int* meta = (int*)(gtmp + (size_t)2 * cap * 384);
    int* ecnt = meta;           // 20
    int* ncnt = ecnt + 20;      // 20
    int* ecur = ncnt + 20;      // 20
    int* ncur = ecur + 20;      // 20
    int* eoff = ncur + 20;      // 21
    int* noff = eoff + 21;      // 21
    int* elist = noff + 21;     // E + 20*TE
    int* nlist = elist + (E + 20 * TE);  // N + 20*TN

    const int* srcA = edge_index;
    const int* dstA = edge_index + E;

    detect_dtype<<<1, 64, 0, stream>>>(hs_init);
    hipMemsetAsync(agg_s, 0, (size_t)2 * ND * sizeof(float), stream);
    hipMemsetAsync(meta, 0, 80 * sizeof(int), stream);
    hipMemsetAsync(elist, 0xFF, (size_t)(E + 20 * TE + N + 20 * TN) * sizeof(int), stream);
    init_state<<<N, D, 0, stream>>>(hs_init, gate, hs, hf);

    int mx = (E > N) ? E : N;
    count_bins<<<(mx + 255) / 256, 256, 0, stream>>>(dstA, gate, lev, E, N, ecnt, ncnt);
    scan_offsets<<<1, 64, 0, stream>>>(ecnt, ncnt, eoff, noff);
    fill_bins<<<(mx + 255) / 256, 256, 0, stream>>>(dstA, gate, lev, E, N,
                                                    eoff, noff, ecur, ncur, elist, nlist);

    int gridE = (E + 20 * TE) / TE + 1;
    int gridNcap = cap / TN;
    for (int level = 1; level < NLEV; ++level) {
        edge_tiles<<<gridE, 256, 0, stream>>>(hs, hf, Ws1, bs1, Ws2, bs2,
                                              Wf1, bf1, Wf2, bf2,
                                              Wnf1, bnf1, Wnf2, bnf2,
                                              srcA, dstA, gate, eoff, elist,
                                              agg_s, agg_f, level);
        node_gemm<<<dim3(gridNcap, 6), 128, 0, stream>>>(agg_s, agg_f, Gs_wih, Gf_wih,
                                                         gate, noff, nlist, gtmp, level, cap);
        node_epi<<<gridNcap, 128, 0, stream>>>(hs, hf, gtmp,
                                               Gs_bih, Gs_bhh, Gf_bih, Gf_bhh,
                                               gate, noff, nlist, level, cap);
    }

    writeout<<<(ND + 255) / 256, 256, 0, stream>>>(hs, hf, d_out, ND);
}

// Round 8
// 571.142 us; speedup vs baseline: 1.0802x; 1.0802x over previous
//
#include <hip/hip_runtime.h>
#include <hip/hip_bf16.h>

typedef __hip_bfloat16 bf16;
typedef unsigned short ushortT;
typedef __attribute__((ext_vector_type(8))) short bf16x8;
typedef __attribute__((ext_vector_type(4))) float f32x4;

#define D 128
#define NLEV 5
#define TE 16  // edges per tile (MFMA M=16)
#define TN 16  // nodes per tile

// weight-transpose blob element offsets (bf16 elements)
#define OFF_S1 0          // [5][128][128]
#define OFF_S2 81920      // [5][128][128]
#define OFF_F1 163840     // [4][128][256]
#define OFF_F2 294912     // [4][128][128]
#define OFF_NF1 360448    // [128][128]
#define OFF_NF2 376832    // [128][128]
#define WT_TOTAL 393216

// gate code -> t (enumerate index in CODES=[3,2,5,1,4]); index 0 unused
__constant__ int TMAP[6] = { -1, 3, 1, 0, 4, 2 };
// gate code -> func-aggregator index (FIDX={3:0,5:1,1:2,4:3}); codes 0,2 unused
__constant__ int FMAP[6] = { -1, 2, -1, 0, 3, 1 };

// dtype flag: 1 = float tensors stored as bf16, 0 = stored as float32
__device__ int g_flag;

__device__ __forceinline__ float sigm(float x) { return 1.0f / (1.0f + __expf(-x)); }

__device__ __forceinline__ float rlane(float v, int ln) {
    return __int_as_float(__builtin_amdgcn_readlane(__float_as_int(v), ln));
}

__device__ __forceinline__ ushortT f2b(float v) {
    bf16 h = __float2bfloat16(v);
    return *reinterpret_cast<ushortT*>(&h);
}

template <int ISB>
__device__ __forceinline__ float ld(const void* p, size_t i) {
    if (ISB) return __bfloat162float(((const bf16*)p)[i]);
    return ((const float*)p)[i];
}

template <int ISB>
__device__ __forceinline__ float2 ld2(const void* p, size_t i) {
    if (ISB) {
        __hip_bfloat162 v = *(const __hip_bfloat162*)((const bf16*)p + i);
        return make_float2(__bfloat162float(v.x), __bfloat162float(v.y));
    }
    return *(const float2*)((const float*)p + i);
}

// ---- dtype sniffer ----
__global__ void detect_dtype(const void* hs_init) {
    int t = threadIdx.x;
    float x = __bfloat162float(((const bf16*)hs_init)[2 * t]);
    float ax = fabsf(x);
    bool sane = (x == 0.0f) || (ax > 1e-4f && ax < 64.0f);
    unsigned long long m = __ballot(sane);
    if (t == 0) g_flag = (__popcll(m) >= 32) ? 1 : 0;
}

// ---- init states: bf16 path uses hsb/hfb, f32 path uses hs/hf ----
__global__ void init_state(const void* __restrict__ hs_init,
                           const int* __restrict__ gate,
                           float* __restrict__ hs, float* __restrict__ hf,
                           ushortT* __restrict__ hsb, ushortT* __restrict__ hfb) {
    int v = blockIdx.x;
    int j = threadIdx.x;
    size_t idx = (size_t)v * D + j;
    bool pi = (gate[v] == 0);
    if (g_flag) {
        hsb[idx] = pi ? ((const ushortT*)hs_init)[idx] : 0;  // raw bf16 copy: exact
        hfb[idx] = 0;
    } else {
        hs[idx] = pi ? ((const float*)hs_init)[idx] : 0.0f;
        hf[idx] = 0.0f;
    }
}

// ---- weight transpose: src [nmat][K][C] bf16 -> dst [nmat][C][K] bf16 ----
__global__ void transpose_w(const ushortT* __restrict__ src, ushortT* __restrict__ dst,
                            int K, int C) {
    if (!g_flag) return;
    int n = blockIdx.y, c = blockIdx.x;
    const ushortT* s = src + (size_t)n * K * C;
    ushortT* d = dst + (size_t)n * C * K;
    for (int k = threadIdx.x; k < K; k += blockDim.x)
        d[(size_t)c * K + k] = s[(size_t)k * C + c];
}

// ================= bucketing: (level-1)*5 + t, levels 1..4 =================
__global__ void count_bins(const int* __restrict__ dstA, const int* __restrict__ gate,
                           const int* __restrict__ lev, int E, int N,
                           int* __restrict__ ecnt, int* __restrict__ ncnt) {
    __shared__ int lc[40];
    int tid = threadIdx.x;
    if (tid < 40) lc[tid] = 0;
    __syncthreads();
    int i = blockIdx.x * blockDim.x + tid;
    if (i < E) {
        int d = dstA[i]; int l = lev[d];
        if (l >= 1 && l < NLEV) atomicAdd(&lc[(l - 1) * 5 + TMAP[gate[d]]], 1);
    }
    if (i < N) {
        int l = lev[i];
        if (l >= 1 && l < NLEV && gate[i] >= 1) atomicAdd(&lc[20 + (l - 1) * 5 + TMAP[gate[i]]], 1);
    }
    __syncthreads();
    if (tid < 20 && lc[tid]) atomicAdd(&ecnt[tid], lc[tid]);
    if (tid >= 20 && tid < 40 && lc[tid]) atomicAdd(&ncnt[tid - 20], lc[tid]);
}

__global__ void scan_offsets(const int* __restrict__ ecnt, const int* __restrict__ ncnt,
                             int* __restrict__ eoff, int* __restrict__ noff) {
    if (threadIdx.x == 0 && blockIdx.x == 0) {
        int o = 0;
        for (int b = 0; b < 20; ++b) { eoff[b] = o; o += ((ecnt[b] + TE - 1) / TE) * TE; }
        eoff[20] = o;
        o = 0;
        for (int b = 0; b < 20; ++b) { noff[b] = o; o += ((ncnt[b] + TN - 1) / TN) * TN; }
        noff[20] = o;
    }
}

__global__ void fill_bins(const int* __restrict__ dstA, const int* __restrict__ gate,
                          const int* __restrict__ lev, int E, int N,
                          const int* __restrict__ eoff, const int* __restrict__ noff,
                          int* __restrict__ ecur, int* __restrict__ ncur,
                          int* __restrict__ elist, int* __restrict__ nlist) {
    __shared__ int ec[20], nc[20], eb[20], nb[20];
    int tid = threadIdx.x;
    if (tid < 20) { ec[tid] = 0; nc[tid] = 0; }
    __syncthreads();
    int i = blockIdx.x * blockDim.x + tid;
    int be = -1, re = 0, bn = -1, rn = 0;
    if (i < E) {
        int d = dstA[i]; int l = lev[d];
        if (l >= 1 && l < NLEV) { be = (l - 1) * 5 + TMAP[gate[d]]; re = atomicAdd(&ec[be], 1); }
    }
    if (i < N) {
        int l = lev[i];
        if (l >= 1 && l < NLEV && gate[i] >= 1) { bn = (l - 1) * 5 + TMAP[gate[i]]; rn = atomicAdd(&nc[bn], 1); }
    }
    __syncthreads();
    if (tid < 20) {
        eb[tid] = ec[tid] ? atomicAdd(&ecur[tid], ec[tid]) : 0;
        nb[tid] = nc[tid] ? atomicAdd(&ncur[tid], nc[tid]) : 0;
    }
    __syncthreads();
    if (be >= 0) elist[eoff[be] + eb[be] + re] = i;
    if (bn >= 0) nlist[noff[bn] + nb[bn] + rn] = i;
}

// ================= MFMA edge pass (bf16 mode) =================
// 4 waves/block: (pass in {struct, func}) x (col-half hc).
// A-frag (16x16x32 bf16): lane l supplies A[l&15][(l>>4)*8 + j], j=0..7
// B-frag: lane l supplies B[(l>>4)*8 + j][l&15]  -> contiguous in W^T[c][k]
// D: lane l holds out[(l>>4)*4 + reg][l&15] (m89-verified mapping)
__global__ __launch_bounds__(256) void edge_mfma(
    const ushortT* __restrict__ hsb, const ushortT* __restrict__ hfb,
    const ushortT* __restrict__ wt,
    const void* __restrict__ bs1, const void* __restrict__ bs2,
    const void* __restrict__ bf1, const void* __restrict__ bf2,
    const void* __restrict__ bnf1, const void* __restrict__ bnf2,
    const int* __restrict__ srcA, const int* __restrict__ dstA,
    const int* __restrict__ gate,
    const int* __restrict__ eoff, const int* __restrict__ elist,
    float* __restrict__ agg_s, float* __restrict__ agg_f, int level) {
    if (!g_flag) return;
    int lo = eoff[(level - 1) * 5];
    int hi = eoff[(level - 1) * 5 + 5];
    int base = lo + blockIdx.x * TE;
    if (base >= hi) return;

    __shared__ int se[TE], de[TE];
    __shared__ bf16 hid[2][16][136];   // 136-pad: rows 272B (16B-aligned, bank-spread)

    int tid = threadIdx.x;
    int wv = tid >> 6, pass = wv >> 1, hc = wv & 1, l = tid & 63;
    int lg = l >> 4, lr = l & 15;

    int c = gate[dstA[elist[base]]];   // uniform over tile (buckets padded)
    int t = TMAP[c], fi = FMAP[c];

    if (tid < TE) {
        int e = elist[base + tid];
        se[tid] = (e < 0) ? -1 : srcA[e];
        de[tid] = (e < 0) ? -1 : dstA[e];
    }
    __syncthreads();

    int src = se[lr];   // A-operand row owned by this lane

    // ---- layer 1 ----
    int KS1; size_t wb1; int K1;
    if (pass == 0)      { KS1 = 4; wb1 = OFF_S1 + (size_t)t * 16384; K1 = 128; }
    else if (c == 2)    { KS1 = 4; wb1 = OFF_NF1; K1 = 128; }
    else                { KS1 = 8; wb1 = OFF_F1 + (size_t)fi * 32768; K1 = 256; }

    f32x4 a0 = {0.f,0.f,0.f,0.f}, a1 = a0, a2 = a0, a3 = a0;
    for (int ks = 0; ks < KS1; ++ks) {
        bf16x8 a = {0,0,0,0,0,0,0,0};
        if (src >= 0) {
            int kk = ks * 32 + lg * 8;
            const ushortT* ap;
            if (pass == 0)      ap = hsb + (size_t)src * D + kk;
            else if (c == 2)    ap = hfb + (size_t)src * D + kk;
            else                ap = (kk < 128) ? (hsb + (size_t)src * D + kk)
                                                : (hfb + (size_t)src * D + (kk - 128));
            a = *(const bf16x8*)ap;
        }
        int kb = ks * 32 + lg * 8;
        {
            bf16x8 b = *(const bf16x8*)&wt[wb1 + (size_t)(hc * 64 + 0 * 16 + lr) * K1 + kb];
            a0 = __builtin_amdgcn_mfma_f32_16x16x32_bf16(a, b, a0, 0, 0, 0);
        }
        {
            bf16x8 b = *(const bf16x8*)&wt[wb1 + (size_t)(hc * 64 + 1 * 16 + lr) * K1 + kb];
            a1 = __builtin_amdgcn_mfma_f32_16x16x32_bf16(a, b, a1, 0, 0, 0);
        }
        {
            bf16x8 b = *(const bf16x8*)&wt[wb1 + (size_t)(hc * 64 + 2 * 16 + lr) * K1 + kb];
            a2 = __builtin_amdgcn_mfma_f32_16x16x32_bf16(a, b, a2, 0, 0, 0);
        }
        {
            bf16x8 b = *(const bf16x8*)&wt[wb1 + (size_t)(hc * 64 + 3 * 16 + lr) * K1 + kb];
            a3 = __builtin_amdgcn_mfma_f32_16x16x32_bf16(a, b, a3, 0, 0, 0);
        }
    }

    // bias + relu -> bf16 hidden in LDS
    const void* b1p = (pass == 0) ? bs1 : (c == 2 ? bnf1 : bf1);
    size_t b1o = (pass == 0) ? (size_t)t * D : (c == 2 ? 0 : (size_t)fi * D);
    {
        f32x4 av[4] = { a0, a1, a2, a3 };
#pragma unroll
        for (int ct = 0; ct < 4; ++ct) {
            int cc = hc * 64 + ct * 16 + lr;
            float bb = ld<1>(b1p, b1o + cc);
#pragma unroll
            for (int r = 0; r < 4; ++r) {
                int m = lg * 4 + r;
                float v = fmaxf(av[ct][r] + bb, 0.f);
                hid[pass][m][cc] = __float2bfloat16(v);
            }
        }
    }
    __syncthreads();

    // ---- layer 2 (K=128 over hidden) ----
    size_t wb2 = (pass == 0) ? (OFF_S2 + (size_t)t * 16384)
                             : (c == 2 ? (size_t)OFF_NF2 : (OFF_F2 + (size_t)fi * 16384));
    a0 = (f32x4){0.f,0.f,0.f,0.f}; a1 = a0; a2 = a0; a3 = a0;
#pragma unroll
    for (int ks = 0; ks < 4; ++ks) {
        bf16x8 a = *(const bf16x8*)&hid[pass][lr][ks * 32 + lg * 8];
        int kb = ks * 32 + lg * 8;
        {
            bf16x8 b = *(const bf16x8*)&wt[wb2 + (size_t)(hc * 64 + 0 * 16 + lr) * 128 + kb];
            a0 = __builtin_amdgcn_mfma_f32_16x16x32_bf16(a, b, a0, 0, 0, 0);
        }
        {
            bf16x8 b = *(const bf16x8*)&wt[wb2 + (size_t)(hc * 64 + 1 * 16 + lr) * 128 + kb];
            a1 = __builtin_amdgcn_mfma_f32_16x16x32_bf16(a, b, a1, 0, 0, 0);
        }
        {
            bf16x8 b = *(const bf16x8*)&wt[wb2 + (size_t)(hc * 64 + 2 * 16 + lr) * 128 + kb];
            a2 = __builtin_amdgcn_mfma_f32_16x16x32_bf16(a, b, a2, 0, 0, 0);
        }
        {
            bf16x8 b = *(const bf16x8*)&wt[wb2 + (size_t)(hc * 64 + 3 * 16 + lr) * 128 + kb];
            a3 = __builtin_amdgcn_mfma_f32_16x16x32_bf16(a, b, a3, 0, 0, 0);
        }
    }

    // per-edge bias + scatter-add
    const void* b2p = (pass == 0) ? bs2 : (c == 2 ? bnf2 : bf2);
    size_t b2o = (pass == 0) ? (size_t)t * D : (c == 2 ? 0 : (size_t)fi * D);
    float* aggp = pass ? agg_f : agg_s;
    {
        f32x4 av[4] = { a0, a1, a2, a3 };
#pragma unroll
        for (int ct = 0; ct < 4; ++ct) {
            int cc = hc * 64 + ct * 16 + lr;
            float bb = ld<1>(b2p, b2o + cc);
#pragma unroll
            for (int r = 0; r < 4; ++r) {
                int m = lg * 4 + r;
                int d = de[m];
                if (d >= 0) atomicAdd(&aggp[(size_t)d * D + cc], av[ct][r] + bb);
            }
        }
    }
}

// ================= f32 fallback edge pass (register-broadcast, from R6) =================
template <int ISB, int K, int R, bool ADD>
__device__ __forceinline__ void mmRL(
    const float (&x0)[R], const float (&x1)[R],
    const void* __restrict__ W, size_t wofs, int wstride,
    const void* __restrict__ B, size_t bofs,
    int c0, float (&out)[R][2]) {
    if (!ADD) {
        float2 b = ld2<ISB>(B, bofs + c0);
#pragma unroll
        for (int r = 0; r < R; ++r) { out[r][0] = b.x; out[r][1] = b.y; }
    }
#pragma unroll 4
    for (int i = 0; i < K; i += 2) {
        float2 w0 = ld2<ISB>(W, wofs + (size_t)i * wstride + c0);
        float2 w1 = ld2<ISB>(W, wofs + ((size_t)i + 1) * wstride + c0);
        int ln = i >> 1;
#pragma unroll
        for (int r = 0; r < R; ++r) {
            float xa = rlane(x0[r], ln);
            float xb = rlane(x1[r], ln);
            out[r][0] = fmaf(xb, w1.x, fmaf(xa, w0.x, out[r][0]));
            out[r][1] = fmaf(xb, w1.y, fmaf(xa, w0.y, out[r][1]));
        }
    }
}

template <int ISB, int MC, int R>
__device__ __forceinline__ void mmB(
    const float (&x0)[R], const float (&x1)[R],
    const void* __restrict__ W, size_t wofs, int wstride,
    int mstart, int c0, float (&out)[R][2]) {
#pragma unroll 4
    for (int mm = 0; mm < MC; ++mm) {
        int m = mstart + mm;
        float2 w0 = ld2<ISB>(W, wofs + (size_t)(2 * m) * wstride + c0);
        float2 w1 = ld2<ISB>(W, wofs + (size_t)(2 * m + 1) * wstride + c0);
#pragma unroll
        for (int r = 0; r < R; ++r) {
            float xa = rlane(x0[r], m);
            float xb = rlane(x1[r], m);
            out[r][0] = fmaf(xb, w1.x, fmaf(xa, w0.x, out[r][0]));
            out[r][1] = fmaf(xb, w1.y, fmaf(xa, w0.y, out[r][1]));
        }
    }
}

__global__ __launch_bounds__(128) void edge_f32(
    const float* __restrict__ hs, const float* __restrict__ hf,
    const void* Ws1, const void* bs1, const void* Ws2, const void* bs2,
    const void* Wf1, const void* bf1, const void* Wf2, const void* bf2,
    const void* Wnf1, const void* bnf1, const void* Wnf2, const void* bnf2,
    const int* srcA, const int* dstA, const int* gate,
    const int* eoff, const int* elist,
    float* agg_s, float* agg_f, int level) {
    if (g_flag) return;
    __shared__ int se[TE], de[TE];
    int lo = eoff[(level - 1) * 5];
    int hi = eoff[(level - 1) * 5 + 5];
    int base = lo + blockIdx.x * TE;
    if (base >= hi) return;
    int tid = threadIdx.x;
    int wv = tid >> 6;
    int l = tid & 63;
    int c0 = 2 * l;
    int c = gate[dstA[elist[base]]];
    int t = TMAP[c];
    if (tid < TE) {
        int e = elist[base + tid];
        se[tid] = (e < 0) ? -1 : srcA[e];
        de[tid] = (e < 0) ? -1 : dstA[e];
    }
    __syncthreads();

    float xs0[TE], xs1[TE], xf0[TE], xf1[TE];
#pragma unroll
    for (int r = 0; r < TE; ++r) {
        int s = se[r];
        float2 v = make_float2(0.f, 0.f);
        if (wv == 0) {
            if (s >= 0) v = *(const float2*)&hs[(size_t)s * D + c0];
            xs0[r] = v.x; xs1[r] = v.y; xf0[r] = 0.f; xf1[r] = 0.f;
        } else {
            if (c != 2 && s >= 0) v = *(const float2*)&hs[(size_t)s * D + c0];
            xs0[r] = v.x; xs1[r] = v.y;
            float2 w = make_float2(0.f, 0.f);
            if (s >= 0) w = *(const float2*)&hf[(size_t)s * D + c0];
            xf0[r] = w.x; xf1[r] = w.y;
        }
    }

    float acc[TE][2];
    if (wv == 0) {
        mmRL<0, 128, TE, false>(xs0, xs1, Ws1, (size_t)t * D * D, D, bs1, (size_t)t * D, c0, acc);
    } else if (c == 2) {
        mmRL<0, 128, TE, false>(xf0, xf1, Wnf1, 0, D, bnf1, 0, c0, acc);
    } else {
        int fi = FMAP[c];
        size_t wofs = (size_t)fi * 2 * D * D;
        mmRL<0, 128, TE, false>(xs0, xs1, Wf1, wofs, D, bf1, (size_t)fi * D, c0, acc);
        mmRL<0, 128, TE, true>(xf0, xf1, Wf1, wofs + (size_t)D * D, D, bf1, (size_t)fi * D, c0, acc);
    }
#pragma unroll
    for (int r = 0; r < TE; ++r) {
        xs0[r] = fmaxf(acc[r][0], 0.f);
        xs1[r] = fmaxf(acc[r][1], 0.f);
    }
    if (wv == 0) {
        mmRL<0, 128, TE, false>(xs0, xs1, Ws2, (size_t)t * D * D, D, bs2, (size_t)t * D, c0, acc);
    } else if (c == 2) {
        mmRL<0, 128, TE, false>(xs0, xs1, Wnf2, 0, D, bnf2, 0, c0, acc);
    } else {
        int fi = FMAP[c];
        mmRL<0, 128, TE, false>(xs0, xs1, Wf2, (size_t)fi * D * D, D, bf2, (size_t)fi * D, c0, acc);
    }
    float* aggp = wv ? agg_f : agg_s;
#pragma unroll
    for (int r = 0; r < TE; ++r) {
        int d = de[r];
        if (d >= 0) {
            atomicAdd(&aggp[(size_t)d * D + c0], acc[r][0]);
            atomicAdd(&aggp[(size_t)d * D + c0 + 1], acc[r][1]);
        }
    }
}

// ===== node GEMM: gi partials; blockIdx.y = p*3 + g; full K=128 per wave (R7, passed) =====
template <int ISB>
__device__ void node_gemm_body(
    const float* __restrict__ agg_s, const float* __restrict__ agg_f,
    const void* __restrict__ Gs_wih, const void* __restrict__ Gf_wih,
    const int* __restrict__ gate,
    const int* __restrict__ noff, const int* __restrict__ nlist,
    float* __restrict__ gtmp, int level, int cap) {
    int lo = noff[(level - 1) * 5];
    int hi = noff[(level - 1) * 5 + 5];
    int base = lo + blockIdx.x * TN;
    if (base >= hi) return;
    int y = blockIdx.y;
    int p = y / 3, g = y % 3;
    int tid = threadIdx.x;
    int wv = tid >> 6;
    int r0 = wv * (TN / 2);
    int l = tid & 63;
    int c0 = 2 * l;
    int cw = g * 128 + c0;
    int t = TMAP[gate[nlist[base]]];

    const float* agg = p ? agg_f : agg_s;
    const void* wih = p ? Gf_wih : Gs_wih;

    float x0[TN / 2], x1[TN / 2];
#pragma unroll
    for (int r = 0; r < TN / 2; ++r) {
        int v = nlist[base + r0 + r];
        float2 a = (v >= 0) ? *(const float2*)&agg[(size_t)v * D + c0]
                            : make_float2(0.f, 0.f);
        x0[r] = a.x; x1[r] = a.y;
    }

    float acc[TN / 2][2];
#pragma unroll
    for (int r = 0; r < TN / 2; ++r) { acc[r][0] = 0.f; acc[r][1] = 0.f; }
    mmB<ISB, 64, TN / 2>(x0, x1, wih, (size_t)t * D * 3 * D, 3 * D, 0, cw, acc);

    size_t tb = ((size_t)p * cap + (base - lo)) * 384 + cw;
#pragma unroll
    for (int r = 0; r < TN / 2; ++r) {
        *(float2*)&gtmp[tb + (size_t)(r0 + r) * 384] = make_float2(acc[r][0], acc[r][1]);
    }
}

__global__ __launch_bounds__(128) void node_gemm(
    const float* agg_s, const float* agg_f,
    const void* Gs_wih, const void* Gf_wih,
    const int* gate, const int* noff, const int* nlist,
    float* gtmp, int level, int cap) {
    if (g_flag)
        node_gemm_body<1>(agg_s, agg_f, Gs_wih, Gf_wih, gate, noff, nlist, gtmp, level, cap);
    else
        node_gemm_body<0>(agg_s, agg_f, Gs_wih, Gf_wih, gate, noff, nlist, gtmp, level, cap);
}

// ===== node epilogue: biases + GRU nonlinearity; writes bf16 states in bf16 mode =====
template <int ISB>
__device__ void node_epi_body(
    float* __restrict__ hs, float* __restrict__ hf,
    ushortT* __restrict__ hsb, ushortT* __restrict__ hfb,
    const float* __restrict__ gtmp,
    const void* __restrict__ Gs_bih, const void* __restrict__ Gs_bhh,
    const void* __restrict__ Gf_bih, const void* __restrict__ Gf_bhh,
    const int* __restrict__ gate,
    const int* __restrict__ noff, const int* __restrict__ nlist,
    int level, int cap) {
    int lo = noff[(level - 1) * 5];
    int hi = noff[(level - 1) * 5 + 5];
    int base = lo + blockIdx.x * TN;
    if (base >= hi) return;
    int j = threadIdx.x;  // 0..127
    int t = TMAP[gate[nlist[base]]];

#pragma unroll
    for (int p = 0; p < 2; ++p) {
        const void* bih = p ? Gf_bih : Gs_bih;
        const void* bhh = p ? Gf_bhh : Gs_bhh;
        float br = ld<ISB>(bih, (size_t)t * 384 + j);
        float bz = ld<ISB>(bih, (size_t)t * 384 + 128 + j);
        float bn = ld<ISB>(bih, (size_t)t * 384 + 256 + j);
        float hr = ld<ISB>(bhh, (size_t)t * 384 + j);
        float hz = ld<ISB>(bhh, (size_t)t * 384 + 128 + j);
        float hn = ld<ISB>(bhh, (size_t)t * 384 + 256 + j);
        const float* g0 = gtmp + (size_t)p * cap * 384;
#pragma unroll
        for (int r = 0; r < TN; ++r) {
            int v = nlist[base + r];
            if (v < 0) continue;
            size_t pos = (size_t)(base - lo + r) * 384;
            float gr = g0[pos + j];
            float gz = g0[pos + 128 + j];
            float gn = g0[pos + 256 + j];
            float rr = sigm(gr + br + hr);
            float z = sigm(gz + bz + hz);
            float n = tanhf(gn + bn + rr * hn);
            float out = (1.f - z) * n;
            if (ISB) {
                ushortT* hb = p ? hfb : hsb;
                hb[(size_t)v * D + j] = f2b(out);
            } else {
                float* ho = p ? hf : hs;
                ho[(size_t)v * D + j] = out;
            }
        }
    }
}

__global__ __launch_bounds__(128) void node_epi(
    float* hs, float* hf, ushortT* hsb, ushortT* hfb, const float* gtmp,
    const void* Gs_bih, const void* Gs_bhh,
    const void* Gf_bih, const void* Gf_bhh,
    const int* gate, const int* noff, const int* nlist, int level, int cap) {
    if (g_flag)
        node_epi_body<1>(hs, hf, hsb, hfb, gtmp, Gs_bih, Gs_bhh, Gf_bih, Gf_bhh,
                         gate, noff, nlist, level, cap);
    else
        node_epi_body<0>(hs, hf, hsb, hfb, gtmp, Gs_bih, Gs_bhh, Gf_bih, Gf_bhh,
                         gate, noff, nlist, level, cap);
}

// ---------------- writeout ----------------
__global__ void writeout(const float* __restrict__ hs, const float* __restrict__ hf,
                         const ushortT* __restrict__ hsb, const ushortT* __restrict__ hfb,
                         void* __restrict__ out, int ND) {
    int i = blockIdx.x * blockDim.x + threadIdx.x;
    if (i >= ND) return;
    if (g_flag) {
        ((ushortT*)out)[i] = hsb[i];
        ((ushortT*)out)[ND + i] = hfb[i];
    } else {
        ((float*)out)[i] = hs[i];
        ((float*)out)[ND + i] = hf[i];
    }
}

extern "C" void kernel_launch(void* const* d_in, const int* in_sizes, int n_in,
                              void* d_out, int out_size, void* d_ws, size_t ws_size,
                              hipStream_t stream) {
    const void* hs_init = d_in[0];
    const void* Ws1 = d_in[1];
    const void* bs1 = d_in[2];
    const void* Ws2 = d_in[3];
    const void* bs2 = d_in[4];
    const void* Wf1 = d_in[5];
    const void* bf1 = d_in[6];
    const void* Wf2 = d_in[7];
    const void* bf2 = d_in[8];
    const void* Wnf1 = d_in[9];
    const void* bnf1 = d_in[10];
    const void* Wnf2 = d_in[11];
    const void* bnf2 = d_in[12];
    const void* Gs_wih = d_in[13];
    const void* Gs_bih = d_in[15];
    const void* Gs_bhh = d_in[16];
    const void* Gf_wih = d_in[17];
    const void* Gf_bih = d_in[19];
    const void* Gf_bhh = d_in[20];
    const int* edge_index = (const int*)d_in[21];
    const int* gate = (const int*)d_in[22];
    const int* lev = (const int*)d_in[23];

    int E = in_sizes[21] / 2;
    int N = in_sizes[22];
    int ND = N * D;
    int cap = ((N / NLEV + 5 * TN + 64) + TN - 1) / TN * TN;

    float* hs = (float*)d_ws;
    float* hf = hs + ND;
    float* agg_s = hf + ND;
    float* agg_f = agg_s + ND;
    float* gtmp = agg_f + ND;                        // 2 * cap * 384 floats
    ushortT* hsb = (ushortT*)(gtmp + (size_t)2 * cap * 384);  // ND ushorts
    ushortT* hfb = hsb + ND;
    ushortT* wt = hfb + ND;                          // WT_TOTAL ushorts
    int* meta = (int*)(wt + WT_TOTAL);
    int* ecnt = meta;           // 20
    int* ncnt = ecnt + 20;      // 20
    int* ecur = ncnt + 20;      // 20
    int* ncur = ecur + 20;      // 20
    int* eoff = ncur + 20;      // 21
    int* noff = eoff + 21;      // 21
    int* elist = noff + 21;     // E + 20*TE
    int* nlist = elist + (E + 20 * TE);  // N + 20*TN

    const int* srcA = edge_index;
    const int* dstA = edge_index + E;

    detect_dtype<<<1, 64, 0, stream>>>(hs_init);
    hipMemsetAsync(agg_s, 0, (size_t)2 * ND * sizeof(float), stream);
    hipMemsetAsync(meta, 0, 80 * sizeof(int), stream);
    hipMemsetAsync(elist, 0xFF, (size_t)(E + 20 * TE + N + 20 * TN) * sizeof(int), stream);
    init_state<<<N, D, 0, stream>>>(hs_init, gate, hs, hf, hsb, hfb);

    // weight transposes (bf16 mode only; no-op otherwise)
    transpose_w<<<dim3(128, 5), 128, 0, stream>>>((const ushortT*)Ws1, wt + OFF_S1, 128, 128);
    transpose_w<<<dim3(128, 5), 128, 0, stream>>>((const ushortT*)Ws2, wt + OFF_S2, 128, 128);
    transpose_w<<<dim3(128, 4), 256, 0, stream>>>((const ushortT*)Wf1, wt + OFF_F1, 256, 128);
    transpose_w<<<dim3(128, 4), 128, 0, stream>>>((const ushortT*)Wf2, wt + OFF_F2, 128, 128);
    transpose_w<<<dim3(128, 1), 128, 0, stream>>>((const ushortT*)Wnf1, wt + OFF_NF1, 128, 128);
    transpose_w<<<dim3(128, 1), 128, 0, stream>>>((const ushortT*)Wnf2, wt + OFF_NF2, 128, 128);

    int mx = (E > N) ? E : N;
    count_bins<<<(mx + 255) / 256, 256, 0, stream>>>(dstA, gate, lev, E, N, ecnt, ncnt);
    scan_offsets<<<1, 64, 0, stream>>>(ecnt, ncnt, eoff, noff);
    fill_bins<<<(mx + 255) / 256, 256, 0, stream>>>(dstA, gate, lev, E, N,
                                                    eoff, noff, ecur, ncur, elist, nlist);

    int gridE = (E + 20 * TE) / TE + 1;
    int gridNcap = cap / TN;
    for (int level = 1; level < NLEV; ++level) {
        edge_mfma<<<gridE, 256, 0, stream>>>(hsb, hfb, wt,
                                             bs1, bs2, bf1, bf2, bnf1, bnf2,
                                             srcA, dstA, gate, eoff, elist,
                                             agg_s, agg_f, level);
        edge_f32<<<gridE, 128, 0, stream>>>(hs, hf, Ws1, bs1, Ws2, bs2,
                                            Wf1, bf1, Wf2, bf2,
                                            Wnf1, bnf1, Wnf2, bnf2,
                                            srcA, dstA, gate, eoff, elist,
                                            agg_s, agg_f, level);
        node_gemm<<<dim3(gridNcap, 6), 128, 0, stream>>>(agg_s, agg_f, Gs_wih, Gf_wih,
                                                         gate, noff, nlist, gtmp, level, cap);
        node_epi<<<gridNcap, 128, 0, stream>>>(hs, hf, hsb, hfb, gtmp,
                                               Gs_bih, Gs_bhh, Gf_bih, Gf_bhh,
                                               gate, noff, nlist, level, cap);
    }

    writeout<<<(ND + 255) / 256, 256, 0, stream>>>(hs, hf, hsb, hfb, d_out, ND);
}

// Round 9
// 398.614 us; speedup vs baseline: 1.5477x; 1.4328x over previous
//
#include <hip/hip_runtime.h>
#include <hip/hip_bf16.h>

typedef __hip_bfloat16 bf16;
typedef unsigned short ushortT;
typedef __attribute__((ext_vector_type(8))) short bf16x8;
typedef __attribute__((ext_vector_type(4))) float f32x4;

#define D 128
#define NLEV 5
#define TE 16  // edges per tile (MFMA M=16)
#define TN 16  // nodes per tile

// weight-transpose blob element offsets (bf16 elements)
#define OFF_S1 0          // [5][128][128]
#define OFF_S2 81920      // [5][128][128]
#define OFF_F1 163840     // [4][128][256]  (W^T: [C=128][K=256])
#define OFF_F2 294912     // [4][128][128]
#define OFF_NF1 360448    // [128][128]
#define OFF_NF2 376832    // [128][128]
#define WT_TOTAL 393216

// gate code -> t (enumerate index in CODES=[3,2,5,1,4]); index 0 unused
__constant__ int TMAP[6] = { -1, 3, 1, 0, 4, 2 };
// gate code -> func-aggregator index (FIDX={3:0,5:1,1:2,4:3}); codes 0,2 unused
__constant__ int FMAP[6] = { -1, 2, -1, 0, 3, 1 };

// dtype flag: 1 = float tensors stored as bf16, 0 = stored as float32
__device__ int g_flag;

__device__ __forceinline__ float sigm(float x) { return 1.0f / (1.0f + __expf(-x)); }

__device__ __forceinline__ float rlane(float v, int ln) {
    return __int_as_float(__builtin_amdgcn_readlane(__float_as_int(v), ln));
}

__device__ __forceinline__ ushortT f2b(float v) {
    bf16 h = __float2bfloat16(v);
    return *reinterpret_cast<ushortT*>(&h);
}

template <int ISB>
__device__ __forceinline__ float ld(const void* p, size_t i) {
    if (ISB) return __bfloat162float(((const bf16*)p)[i]);
    return ((const float*)p)[i];
}

template <int ISB>
__device__ __forceinline__ float2 ld2(const void* p, size_t i) {
    if (ISB) {
        __hip_bfloat162 v = *(const __hip_bfloat162*)((const bf16*)p + i);
        return make_float2(__bfloat162float(v.x), __bfloat162float(v.y));
    }
    return *(const float2*)((const float*)p + i);
}

// ---- dtype sniffer ----
__global__ void detect_dtype(const void* hs_init) {
    int t = threadIdx.x;
    float x = __bfloat162float(((const bf16*)hs_init)[2 * t]);
    float ax = fabsf(x);
    bool sane = (x == 0.0f) || (ax > 1e-4f && ax < 64.0f);
    unsigned long long m = __ballot(sane);
    if (t == 0) g_flag = (__popcll(m) >= 32) ? 1 : 0;
}

// ---- init: f32 canonical states + bf16 mirrors, both dtypes ----
__global__ void init_state(const void* __restrict__ hs_init,
                           const int* __restrict__ gate,
                           float* __restrict__ hs, float* __restrict__ hf,
                           ushortT* __restrict__ hsb, ushortT* __restrict__ hfb) {
    int v = blockIdx.x;
    int j = threadIdx.x;
    size_t idx = (size_t)v * D + j;
    bool pi = (gate[v] == 0);
    float val = 0.f;
    ushortT bval = 0;
    if (pi) {
        if (g_flag) {
            bval = ((const ushortT*)hs_init)[idx];      // exact bf16 copy
            bf16 h = *reinterpret_cast<bf16*>(&bval);
            val = __bfloat162float(h);                  // exact widen
        } else {
            val = ((const float*)hs_init)[idx];
            bval = f2b(val);                            // rounded mirror
        }
    }
    hs[idx] = val; hf[idx] = 0.f;
    hsb[idx] = bval; hfb[idx] = 0;
}

// ---- weight transpose+convert: src [nmat][K][C] -> dst bf16 [nmat][C][K] ----
__global__ void transpose_w(const void* __restrict__ src, ushortT* __restrict__ dst,
                            int K, int C) {
    int n = blockIdx.y, c = blockIdx.x;
    ushortT* d = dst + (size_t)n * C * K;
    if (g_flag) {
        const ushortT* s = (const ushortT*)src + (size_t)n * K * C;
        for (int k = threadIdx.x; k < K; k += blockDim.x)
            d[(size_t)c * K + k] = s[(size_t)k * C + c];
    } else {
        const float* s = (const float*)src + (size_t)n * K * C;
        for (int k = threadIdx.x; k < K; k += blockDim.x)
            d[(size_t)c * K + k] = f2b(s[(size_t)k * C + c]);
    }
}

// ================= bucketing: (level-1)*5 + t, levels 1..4 =================
__global__ void count_bins(const int* __restrict__ dstA, const int* __restrict__ gate,
                           const int* __restrict__ lev, int E, int N,
                           int* __restrict__ ecnt, int* __restrict__ ncnt) {
    __shared__ int lc[40];
    int tid = threadIdx.x;
    if (tid < 40) lc[tid] = 0;
    __syncthreads();
    int i = blockIdx.x * blockDim.x + tid;
    if (i < E) {
        int d = dstA[i]; int l = lev[d];
        if (l >= 1 && l < NLEV) atomicAdd(&lc[(l - 1) * 5 + TMAP[gate[d]]], 1);
    }
    if (i < N) {
        int l = lev[i];
        if (l >= 1 && l < NLEV && gate[i] >= 1) atomicAdd(&lc[20 + (l - 1) * 5 + TMAP[gate[i]]], 1);
    }
    __syncthreads();
    if (tid < 20 && lc[tid]) atomicAdd(&ecnt[tid], lc[tid]);
    if (tid >= 20 && tid < 40 && lc[tid]) atomicAdd(&ncnt[tid - 20], lc[tid]);
}

__global__ void scan_offsets(const int* __restrict__ ecnt, const int* __restrict__ ncnt,
                             int* __restrict__ eoff, int* __restrict__ noff) {
    if (threadIdx.x == 0 && blockIdx.x == 0) {
        int o = 0;
        for (int b = 0; b < 20; ++b) { eoff[b] = o; o += ((ecnt[b] + TE - 1) / TE) * TE; }
        eoff[20] = o;
        o = 0;
        for (int b = 0; b < 20; ++b) { noff[b] = o; o += ((ncnt[b] + TN - 1) / TN) * TN; }
        noff[20] = o;
    }
}

__global__ void fill_bins(const int* __restrict__ dstA, const int* __restrict__ gate,
                          const int* __restrict__ lev, int E, int N,
                          const int* __restrict__ eoff, const int* __restrict__ noff,
                          int* __restrict__ ecur, int* __restrict__ ncur,
                          int* __restrict__ elist, int* __restrict__ nlist) {
    __shared__ int ec[20], nc[20], eb[20], nb[20];
    int tid = threadIdx.x;
    if (tid < 20) { ec[tid] = 0; nc[tid] = 0; }
    __syncthreads();
    int i = blockIdx.x * blockDim.x + tid;
    int be = -1, re = 0, bn = -1, rn = 0;
    if (i < E) {
        int d = dstA[i]; int l = lev[d];
        if (l >= 1 && l < NLEV) { be = (l - 1) * 5 + TMAP[gate[d]]; re = atomicAdd(&ec[be], 1); }
    }
    if (i < N) {
        int l = lev[i];
        if (l >= 1 && l < NLEV && gate[i] >= 1) { bn = (l - 1) * 5 + TMAP[gate[i]]; rn = atomicAdd(&nc[bn], 1); }
    }
    __syncthreads();
    if (tid < 20) {
        eb[tid] = ec[tid] ? atomicAdd(&ecur[tid], ec[tid]) : 0;
        nb[tid] = nc[tid] ? atomicAdd(&ncur[tid], nc[tid]) : 0;
    }
    __syncthreads();
    if (be >= 0) elist[eoff[be] + eb[be] + re] = i;
    if (bn >= 0) nlist[noff[bn] + nb[bn] + rn] = i;
}

// ================= MFMA edge pass (both dtypes; states via bf16 mirrors) =================
// 4 waves/block: (pass in {struct, func}) x (col-half hc).
// A-frag (16x16x32 bf16): lane l supplies A[l&15][(l>>4)*8 + j], j=0..7
// B-frag: lane l supplies B[(l>>4)*8 + j][l&15]  -> contiguous in W^T[c][k]
// D: lane l holds out[(l>>4)*4 + reg][l&15] (m89-verified mapping)
__global__ __launch_bounds__(256) void edge_mfma(
    const ushortT* __restrict__ hsb, const ushortT* __restrict__ hfb,
    const ushortT* __restrict__ wt,
    const void* __restrict__ bs1, const void* __restrict__ bs2,
    const void* __restrict__ bf1, const void* __restrict__ bf2,
    const void* __restrict__ bnf1, const void* __restrict__ bnf2,
    const int* __restrict__ dstA, const int* __restrict__ srcA,
    const int* __restrict__ gate,
    const int* __restrict__ eoff, const int* __restrict__ elist,
    float* __restrict__ agg_s, float* __restrict__ agg_f, int level) {
    int lo = eoff[(level - 1) * 5];
    int hi = eoff[(level - 1) * 5 + 5];
    int base = lo + blockIdx.x * TE;
    if (base >= hi) return;

    __shared__ int se[TE], de[TE];
    __shared__ bf16 hid[2][16][136];   // 272B rows: 16B-aligned, 2-way bank alias (free)

    int tid = threadIdx.x;
    int wv = tid >> 6, pass = wv >> 1, hc = wv & 1, l = tid & 63;
    int lg = l >> 4, lr = l & 15;
    int isb = g_flag;

    int c = gate[dstA[elist[base]]];   // uniform over tile (buckets padded)
    int t = TMAP[c], fi = FMAP[c];

    if (tid < TE) {
        int e = elist[base + tid];
        se[tid] = (e < 0) ? -1 : srcA[e];
        de[tid] = (e < 0) ? -1 : dstA[e];
    }
    __syncthreads();

    int src = se[lr];   // A-operand row owned by this lane

    // ---- layer 1 ----
    int KS1; size_t wb1; int K1;
    if (pass == 0)      { KS1 = 4; wb1 = OFF_S1 + (size_t)t * 16384; K1 = 128; }
    else if (c == 2)    { KS1 = 4; wb1 = OFF_NF1; K1 = 128; }
    else                { KS1 = 8; wb1 = OFF_F1 + (size_t)fi * 32768; K1 = 256; }

    f32x4 a0 = {0.f,0.f,0.f,0.f}, a1 = a0, a2 = a0, a3 = a0;
    for (int ks = 0; ks < KS1; ++ks) {
        bf16x8 a = {0,0,0,0,0,0,0,0};
        if (src >= 0) {
            int kk = ks * 32 + lg * 8;
            const ushortT* ap;
            if (pass == 0)      ap = hsb + (size_t)src * D + kk;
            else if (c == 2)    ap = hfb + (size_t)src * D + kk;
            else                ap = (kk < 128) ? (hsb + (size_t)src * D + kk)
                                                : (hfb + (size_t)src * D + (kk - 128));
            a = *(const bf16x8*)ap;
        }
        int kb = ks * 32 + lg * 8;
        {
            bf16x8 b = *(const bf16x8*)&wt[wb1 + (size_t)(hc * 64 + 0 * 16 + lr) * K1 + kb];
            a0 = __builtin_amdgcn_mfma_f32_16x16x32_bf16(a, b, a0, 0, 0, 0);
        }
        {
            bf16x8 b = *(const bf16x8*)&wt[wb1 + (size_t)(hc * 64 + 1 * 16 + lr) * K1 + kb];
            a1 = __builtin_amdgcn_mfma_f32_16x16x32_bf16(a, b, a1, 0, 0, 0);
        }
        {
            bf16x8 b = *(const bf16x8*)&wt[wb1 + (size_t)(hc * 64 + 2 * 16 + lr) * K1 + kb];
            a2 = __builtin_amdgcn_mfma_f32_16x16x32_bf16(a, b, a2, 0, 0, 0);
        }
        {
            bf16x8 b = *(const bf16x8*)&wt[wb1 + (size_t)(hc * 64 + 3 * 16 + lr) * K1 + kb];
            a3 = __builtin_amdgcn_mfma_f32_16x16x32_bf16(a, b, a3, 0, 0, 0);
        }
    }

    // bias + relu -> bf16 hidden in LDS
    const void* b1p = (pass == 0) ? bs1 : (c == 2 ? bnf1 : bf1);
    size_t b1o = (pass == 0) ? (size_t)t * D : (c == 2 ? 0 : (size_t)fi * D);
    {
        f32x4 av[4] = { a0, a1, a2, a3 };
#pragma unroll
        for (int ct = 0; ct < 4; ++ct) {
            int cc = hc * 64 + ct * 16 + lr;
            float bb = isb ? ld<1>(b1p, b1o + cc) : ld<0>(b1p, b1o + cc);
#pragma unroll
            for (int r = 0; r < 4; ++r) {
                int m = lg * 4 + r;
                float v = fmaxf(av[ct][r] + bb, 0.f);
                hid[pass][m][cc] = __float2bfloat16(v);
            }
        }
    }
    __syncthreads();

    // ---- layer 2 (K=128 over hidden) ----
    size_t wb2 = (pass == 0) ? (OFF_S2 + (size_t)t * 16384)
                             : (c == 2 ? (size_t)OFF_NF2 : (OFF_F2 + (size_t)fi * 16384));
    a0 = (f32x4){0.f,0.f,0.f,0.f}; a1 = a0; a2 = a0; a3 = a0;
#pragma unroll
    for (int ks = 0; ks < 4; ++ks) {
        bf16x8 a = *(const bf16x8*)&hid[pass][lr][ks * 32 + lg * 8];
        int kb = ks * 32 + lg * 8;
        {
            bf16x8 b = *(const bf16x8*)&wt[wb2 + (size_t)(hc * 64 + 0 * 16 + lr) * 128 + kb];
            a0 = __builtin_amdgcn_mfma_f32_16x16x32_bf16(a, b, a0, 0, 0, 0);
        }
        {
            bf16x8 b = *(const bf16x8*)&wt[wb2 + (size_t)(hc * 64 + 1 * 16 + lr) * 128 + kb];
            a1 = __builtin_amdgcn_mfma_f32_16x16x32_bf16(a, b, a1, 0, 0, 0);
        }
        {
            bf16x8 b = *(const bf16x8*)&wt[wb2 + (size_t)(hc * 64 + 2 * 16 + lr) * 128 + kb];
            a2 = __builtin_amdgcn_mfma_f32_16x16x32_bf16(a, b, a2, 0, 0, 0);
        }
        {
            bf16x8 b = *(const bf16x8*)&wt[wb2 + (size_t)(hc * 64 + 3 * 16 + lr) * 128 + kb];
            a3 = __builtin_amdgcn_mfma_f32_16x16x32_bf16(a, b, a3, 0, 0, 0);
        }
    }

    // per-edge bias + scatter-add
    const void* b2p = (pass == 0) ? bs2 : (c == 2 ? bnf2 : bf2);
    size_t b2o = (pass == 0) ? (size_t)t * D : (c == 2 ? 0 : (size_t)fi * D);
    float* aggp = pass ? agg_f : agg_s;
    {
        f32x4 av[4] = { a0, a1, a2, a3 };
#pragma unroll
        for (int ct = 0; ct < 4; ++ct) {
            int cc = hc * 64 + ct * 16 + lr;
            float bb = isb ? ld<1>(b2p, b2o + cc) : ld<0>(b2p, b2o + cc);
#pragma unroll
            for (int r = 0; r < 4; ++r) {
                int m = lg * 4 + r;
                int d = de[m];
                if (d >= 0) atomicAdd(&aggp[(size_t)d * D + cc], av[ct][r] + bb);
            }
        }
    }
}

// ===== node GEMM: gi partials; blockIdx.y = p*3 + g; full K=128 per wave (f32) =====
template <int ISB, int MC, int R>
__device__ __forceinline__ void mmB(
    const float (&x0)[R], const float (&x1)[R],
    const void* __restrict__ W, size_t wofs, int wstride,
    int mstart, int c0, float (&out)[R][2]) {
#pragma unroll 4
    for (int mm = 0; mm < MC; ++mm) {
        int m = mstart + mm;
        float2 w0 = ld2<ISB>(W, wofs + (size_t)(2 * m) * wstride + c0);
        float2 w1 = ld2<ISB>(W, wofs + (size_t)(2 * m + 1) * wstride + c0);
#pragma unroll
        for (int r = 0; r < R; ++r) {
            float xa = rlane(x0[r], m);
            float xb = rlane(x1[r], m);
            out[r][0] = fmaf(xb, w1.x, fmaf(xa, w0.x, out[r][0]));
            out[r][1] = fmaf(xb, w1.y, fmaf(xa, w0.y, out[r][1]));
        }
    }
}

template <int ISB>
__device__ void node_gemm_body(
    const float* __restrict__ agg_s, const float* __restrict__ agg_f,
    const void* __restrict__ Gs_wih, const void* __restrict__ Gf_wih,
    const int* __restrict__ gate,
    const int* __restrict__ noff, const int* __restrict__ nlist,
    float* __restrict__ gtmp, int level, int cap) {
    int lo = noff[(level - 1) * 5];
    int hi = noff[(level - 1) * 5 + 5];
    int base = lo + blockIdx.x * TN;
    if (base >= hi) return;
    int y = blockIdx.y;
    int p = y / 3, g = y % 3;
    int tid = threadIdx.x;
    int wv = tid >> 6;
    int r0 = wv * (TN / 2);
    int l = tid & 63;
    int c0 = 2 * l;
    int cw = g * 128 + c0;
    int t = TMAP[gate[nlist[base]]];

    const float* agg = p ? agg_f : agg_s;
    const void* wih = p ? Gf_wih : Gs_wih;

    float x0[TN / 2], x1[TN / 2];
#pragma unroll
    for (int r = 0; r < TN / 2; ++r) {
        int v = nlist[base + r0 + r];
        float2 a = (v >= 0) ? *(const float2*)&agg[(size_t)v * D + c0]
                            : make_float2(0.f, 0.f);
        x0[r] = a.x; x1[r] = a.y;
    }

    float acc[TN / 2][2];
#pragma unroll
    for (int r = 0; r < TN / 2; ++r) { acc[r][0] = 0.f; acc[r][1] = 0.f; }
    mmB<ISB, 64, TN / 2>(x0, x1, wih, (size_t)t * D * 3 * D, 3 * D, 0, cw, acc);

    size_t tb = ((size_t)p * cap + (base - lo)) * 384 + cw;
#pragma unroll
    for (int r = 0; r < TN / 2; ++r) {
        *(float2*)&gtmp[tb + (size_t)(r0 + r) * 384] = make_float2(acc[r][0], acc[r][1]);
    }
}

__global__ __launch_bounds__(128) void node_gemm(
    const float* agg_s, const float* agg_f,
    const void* Gs_wih, const void* Gf_wih,
    const int* gate, const int* noff, const int* nlist,
    float* gtmp, int level, int cap) {
    if (g_flag)
        node_gemm_body<1>(agg_s, agg_f, Gs_wih, Gf_wih, gate, noff, nlist, gtmp, level, cap);
    else
        node_gemm_body<0>(agg_s, agg_f, Gs_wih, Gf_wih, gate, noff, nlist, gtmp, level, cap);
}

// ===== node epilogue: biases + GRU nonlinearity; writes f32 + bf16 mirrors =====
template <int ISB>
__device__ void node_epi_body(
    float* __restrict__ hs, float* __restrict__ hf,
    ushortT* __restrict__ hsb, ushortT* __restrict__ hfb,
    const float* __restrict__ gtmp,
    const void* __restrict__ Gs_bih, const void* __restrict__ Gs_bhh,
    const void* __restrict__ Gf_bih, const void* __restrict__ Gf_bhh,
    const int* __restrict__ gate,
    const int* __restrict__ noff, const int* __restrict__ nlist,
    int level, int cap) {
    int lo = noff[(level - 1) * 5];
    int hi = noff[(level - 1) * 5 + 5];
    int base = lo + blockIdx.x * TN;
    if (base >= hi) return;
    int j = threadIdx.x;  // 0..127
    int t = TMAP[gate[nlist[base]]];

#pragma unroll
    for (int p = 0; p < 2; ++p) {
        const void* bih = p ? Gf_bih : Gs_bih;
        const void* bhh = p ? Gf_bhh : Gs_bhh;
        float br = ld<ISB>(bih, (size_t)t * 384 + j);
        float bz = ld<ISB>(bih, (size_t)t * 384 + 128 + j);
        float bn = ld<ISB>(bih, (size_t)t * 384 + 256 + j);
        float hr = ld<ISB>(bhh, (size_t)t * 384 + j);
        float hz = ld<ISB>(bhh, (size_t)t * 384 + 128 + j);
        float hn = ld<ISB>(bhh, (size_t)t * 384 + 256 + j);
        const float* g0 = gtmp + (size_t)p * cap * 384;
        float* ho = p ? hf : hs;
        ushortT* hb = p ? hfb : hsb;
#pragma unroll
        for (int r = 0; r < TN; ++r) {
            int v = nlist[base + r];
            if (v < 0) continue;
            size_t pos = (size_t)(base - lo + r) * 384;
            float gr = g0[pos + j];
            float gz = g0[pos + 128 + j];
            float gn = g0[pos + 256 + j];
            float rr = sigm(gr + br + hr);
            float z = sigm(gz + bz + hz);
            float n = tanhf(gn + bn + rr * hn);
            float out = (1.f - z) * n;
            ho[(size_t)v * D + j] = out;
            hb[(size_t)v * D + j] = f2b(out);
        }
    }
}

__global__ __launch_bounds__(128) void node_epi(
    float* hs, float* hf, ushortT* hsb, ushortT* hfb, const float* gtmp,
    const void* Gs_bih, const void* Gs_bhh,
    const void* Gf_bih, const void* Gf_bhh,
    const int* gate, const int* noff, const int* nlist, int level, int cap) {
    if (g_flag)
        node_epi_body<1>(hs, hf, hsb, hfb, gtmp, Gs_bih, Gs_bhh, Gf_bih, Gf_bhh,
                         gate, noff, nlist, level, cap);
    else
        node_epi_body<0>(hs, hf, hsb, hfb, gtmp, Gs_bih, Gs_bhh, Gf_bih, Gf_bhh,
                         gate, noff, nlist, level, cap);
}

// ---------------- writeout: from f32 canonical ----------------
__global__ void writeout(const float* __restrict__ hs, const float* __restrict__ hf,
                         void* __restrict__ out, int ND) {
    int i = blockIdx.x * blockDim.x + threadIdx.x;
    if (i >= ND) return;
    if (g_flag) {
        ((ushortT*)out)[i] = f2b(hs[i]);
        ((ushortT*)out)[ND + i] = f2b(hf[i]);
    } else {
        ((float*)out)[i] = hs[i];
        ((float*)out)[ND + i] = hf[i];
    }
}

extern "C" void kernel_launch(void* const* d_in, const int* in_sizes, int n_in,
                              void* d_out, int out_size, void* d_ws, size_t ws_size,
                              hipStream_t stream) {
    const void* hs_init = d_in[0];
    const void* Ws1 = d_in[1];
    const void* bs1 = d_in[2];
    const void* Ws2 = d_in[3];
    const void* bs2 = d_in[4];
    const void* Wf1 = d_in[5];
    const void* bf1 = d_in[6];
    const void* Wf2 = d_in[7];
    const void* bf2 = d_in[8];
    const void* Wnf1 = d_in[9];
    const void* bnf1 = d_in[10];
    const void* Wnf2 = d_in[11];
    const void* bnf2 = d_in[12];
    const void* Gs_wih = d_in[13];
    const void* Gs_bih = d_in[15];
    const void* Gs_bhh = d_in[16];
    const void* Gf_wih = d_in[17];
    const void* Gf_bih = d_in[19];
    const void* Gf_bhh = d_in[20];
    const int* edge_index = (const int*)d_in[21];
    const int* gate = (const int*)d_in[22];
    const int* lev = (const int*)d_in[23];

    int E = in_sizes[21] / 2;
    int N = in_sizes[22];
    int ND = N * D;
    int cap = ((N / NLEV + 5 * TN + 64) + TN - 1) / TN * TN;

    float* hs = (float*)d_ws;
    float* hf = hs + ND;
    float* agg_s = hf + ND;
    float* agg_f = agg_s + ND;
    float* gtmp = agg_f + ND;                        // 2 * cap * 384 floats
    ushortT* hsb = (ushortT*)(gtmp + (size_t)2 * cap * 384);  // ND ushorts
    ushortT* hfb = hsb + ND;
    ushortT* wt = hfb + ND;                          // WT_TOTAL ushorts
    int* meta = (int*)(wt + WT_TOTAL);
    int* ecnt = meta;           // 20
    int* ncnt = ecnt + 20;      // 20
    int* ecur = ncnt + 20;      // 20
    int* ncur = ecur + 20;      // 20
    int* eoff = ncur + 20;      // 21
    int* noff = eoff + 21;      // 21
    int* elist = noff + 21;     // E + 20*TE
    int* nlist = elist + (E + 20 * TE);  // N + 20*TN

    const int* srcA = edge_index;
    const int* dstA = edge_index + E;

    detect_dtype<<<1, 64, 0, stream>>>(hs_init);
    hipMemsetAsync(agg_s, 0, (size_t)2 * ND * sizeof(float), stream);
    hipMemsetAsync(meta, 0, 80 * sizeof(int), stream);
    hipMemsetAsync(elist, 0xFF, (size_t)(E + 20 * TE + N + 20 * TN) * sizeof(int), stream);
    init_state<<<N, D, 0, stream>>>(hs_init, gate, hs, hf, hsb, hfb);

    // weight transposes + bf16 conversion (both dtypes)
    transpose_w<<<dim3(128, 5), 128, 0, stream>>>(Ws1, wt + OFF_S1, 128, 128);
    transpose_w<<<dim3(128, 5), 128, 0, stream>>>(Ws2, wt + OFF_S2, 128, 128);
    transpose_w<<<dim3(128, 4), 256, 0, stream>>>(Wf1, wt + OFF_F1, 256, 128);
    transpose_w<<<dim3(128, 4), 128, 0, stream>>>(Wf2, wt + OFF_F2, 128, 128);
    transpose_w<<<dim3(128, 1), 128, 0, stream>>>(Wnf1, wt + OFF_NF1, 128, 128);
    transpose_w<<<dim3(128, 1), 128, 0, stream>>>(Wnf2, wt + OFF_NF2, 128, 128);

    int mx = (E > N) ? E : N;
    count_bins<<<(mx + 255) / 256, 256, 0, stream>>>(dstA, gate, lev, E, N, ecnt, ncnt);
    scan_offsets<<<1, 64, 0, stream>>>(ecnt, ncnt, eoff, noff);
    fill_bins<<<(mx + 255) / 256, 256, 0, stream>>>(dstA, gate, lev, E, N,
                                                    eoff, noff, ecur, ncur, elist, nlist);

    int gridE = (E + 20 * TE) / TE + 1;
    int gridNcap = cap / TN;
    for (int level = 1; level < NLEV; ++level) {
        edge_mfma<<<gridE, 256, 0, stream>>>(hsb, hfb, wt,
                                             bs1, bs2, bf1, bf2, bnf1, bnf2,
                                             dstA, srcA, gate, eoff, elist,
                                             agg_s, agg_f, level);
        node_gemm<<<dim3(gridNcap, 6), 128, 0, stream>>>(agg_s, agg_f, Gs_wih, Gf_wih,
                                                         gate, noff, nlist, gtmp, level, cap);
        node_epi<<<gridNcap, 128, 0, stream>>>(hs, hf, hsb, hfb, gtmp,
                                               Gs_bih, Gs_bhh, Gf_bih, Gf_bhh,
                                               gate, noff, nlist, level, cap);
    }

    writeout<<<(ND + 255) / 256, 256, 0, stream>>>(hs, hf, d_out, ND);
}

// Round 10
// 302.214 us; speedup vs baseline: 2.0414x; 1.3190x over previous
//
#include <hip/hip_runtime.h>
#include <hip/hip_bf16.h>

typedef __hip_bfloat16 bf16;
typedef unsigned short ushortT;
typedef __attribute__((ext_vector_type(8))) short bf16x8;
typedef __attribute__((ext_vector_type(4))) float f32x4;

#define D 128
#define NLEV 5
#define TE 16  // edges per tile (MFMA M=16)
#define TN 16  // nodes per tile

// weight-transpose blob element offsets (bf16 elements)
#define OFF_S1 0          // [5][128][128]
#define OFF_S2 81920      // [5][128][128]
#define OFF_F1 163840     // [4][128][256]  (W^T: [C=128][K=256])
#define OFF_F2 294912     // [4][128][128]
#define OFF_NF1 360448    // [128][128]
#define OFF_NF2 376832    // [128][128]
#define WT_TOTAL 393216

// gate code -> t (enumerate index in CODES=[3,2,5,1,4]); index 0 unused
__constant__ int TMAP[6] = { -1, 3, 1, 0, 4, 2 };
// gate code -> func-aggregator index (FIDX={3:0,5:1,1:2,4:3}); codes 0,2 unused
__constant__ int FMAP[6] = { -1, 2, -1, 0, 3, 1 };

// dtype flag: 1 = float tensors stored as bf16, 0 = stored as float32
__device__ int g_flag;

__device__ __forceinline__ float sigm(float x) { return 1.0f / (1.0f + __expf(-x)); }

__device__ __forceinline__ float rlane(float v, int ln) {
    return __int_as_float(__builtin_amdgcn_readlane(__float_as_int(v), ln));
}

__device__ __forceinline__ ushortT f2b(float v) {
    bf16 h = __float2bfloat16(v);
    return *reinterpret_cast<ushortT*>(&h);
}

template <int ISB>
__device__ __forceinline__ float ld(const void* p, size_t i) {
    if (ISB) return __bfloat162float(((const bf16*)p)[i]);
    return ((const float*)p)[i];
}

template <int ISB>
__device__ __forceinline__ float2 ld2(const void* p, size_t i) {
    if (ISB) {
        __hip_bfloat162 v = *(const __hip_bfloat162*)((const bf16*)p + i);
        return make_float2(__bfloat162float(v.x), __bfloat162float(v.y));
    }
    return *(const float2*)((const float*)p + i);
}

// ---- dtype sniffer ----
__global__ void detect_dtype(const void* hs_init) {
    int t = threadIdx.x;
    float x = __bfloat162float(((const bf16*)hs_init)[2 * t]);
    float ax = fabsf(x);
    bool sane = (x == 0.0f) || (ax > 1e-4f && ax < 64.0f);
    unsigned long long m = __ballot(sane);
    if (t == 0) g_flag = (__popcll(m) >= 32) ? 1 : 0;
}

// ---- init: f32 canonical states + bf16 mirrors ----
__global__ void init_state(const void* __restrict__ hs_init,
                           const int* __restrict__ gate,
                           float* __restrict__ hs, float* __restrict__ hf,
                           ushortT* __restrict__ hsb, ushortT* __restrict__ hfb) {
    int v = blockIdx.x;
    int j = threadIdx.x;
    size_t idx = (size_t)v * D + j;
    bool pi = (gate[v] == 0);
    float val = 0.f;
    ushortT bval = 0;
    if (pi) {
        if (g_flag) {
            bval = ((const ushortT*)hs_init)[idx];
            bf16 h = *reinterpret_cast<bf16*>(&bval);
            val = __bfloat162float(h);
        } else {
            val = ((const float*)hs_init)[idx];
            bval = f2b(val);
        }
    }
    hs[idx] = val; hf[idx] = 0.f;
    hsb[idx] = bval; hfb[idx] = 0;
}

// ---- weight transpose+convert: src [nmat][K][C] -> dst bf16 [nmat][C][K] ----
__global__ void transpose_w(const void* __restrict__ src, ushortT* __restrict__ dst,
                            int K, int C) {
    int n = blockIdx.y, c = blockIdx.x;
    ushortT* d = dst + (size_t)n * C * K;
    if (g_flag) {
        const ushortT* s = (const ushortT*)src + (size_t)n * K * C;
        for (int k = threadIdx.x; k < K; k += blockDim.x)
            d[(size_t)c * K + k] = s[(size_t)k * C + c];
    } else {
        const float* s = (const float*)src + (size_t)n * K * C;
        for (int k = threadIdx.x; k < K; k += blockDim.x)
            d[(size_t)c * K + k] = f2b(s[(size_t)k * C + c]);
    }
}

// ========== bucketing: (level-1)*5 + t, levels 1..4; edges dst-grouped ==========
__global__ void count_bins(const int* __restrict__ dstA, const int* __restrict__ gate,
                           const int* __restrict__ lev, int E, int N,
                           int* __restrict__ ecnt, int* __restrict__ ncnt,
                           int* __restrict__ ndeg) {
    __shared__ int lc[40];
    int tid = threadIdx.x;
    if (tid < 40) lc[tid] = 0;
    __syncthreads();
    int i = blockIdx.x * blockDim.x + tid;
    if (i < E) {
        int d = dstA[i]; int l = lev[d];
        if (l >= 1 && l < NLEV) {
            atomicAdd(&lc[(l - 1) * 5 + TMAP[gate[d]]], 1);
            atomicAdd(&ndeg[d], 1);
        }
    }
    if (i < N) {
        int l = lev[i];
        if (l >= 1 && l < NLEV && gate[i] >= 1) atomicAdd(&lc[20 + (l - 1) * 5 + TMAP[gate[i]]], 1);
    }
    __syncthreads();
    if (tid < 20 && lc[tid]) atomicAdd(&ecnt[tid], lc[tid]);
    if (tid >= 20 && tid < 40 && lc[tid]) atomicAdd(&ncnt[tid - 20], lc[tid]);
}

__global__ void scan_offsets(const int* __restrict__ ecnt, const int* __restrict__ ncnt,
                             int* __restrict__ eoff, int* __restrict__ noff) {
    if (threadIdx.x == 0 && blockIdx.x == 0) {
        int o = 0;
        for (int b = 0; b < 20; ++b) { eoff[b] = o; o += ((ecnt[b] + TE - 1) / TE) * TE; }
        eoff[20] = o;
        o = 0;
        for (int b = 0; b < 20; ++b) { noff[b] = o; o += ((ncnt[b] + TN - 1) / TN) * TN; }
        noff[20] = o;
    }
}

// nodes -> nlist (bucketed, padded with -1)
__global__ void fill_bins(const int* __restrict__ gate, const int* __restrict__ lev, int N,
                          const int* __restrict__ noff, int* __restrict__ ncur,
                          int* __restrict__ nlist) {
    __shared__ int nc[20], nb[20];
    int tid = threadIdx.x;
    if (tid < 20) nc[tid] = 0;
    __syncthreads();
    int i = blockIdx.x * blockDim.x + tid;
    int bn = -1, rn = 0;
    if (i < N) {
        int l = lev[i];
        if (l >= 1 && l < NLEV && gate[i] >= 1) { bn = (l - 1) * 5 + TMAP[gate[i]]; rn = atomicAdd(&nc[bn], 1); }
    }
    __syncthreads();
    if (tid < 20) nb[tid] = nc[tid] ? atomicAdd(&ncur[tid], nc[tid]) : 0;
    __syncthreads();
    if (bn >= 0) nlist[noff[bn] + nb[bn] + rn] = i;
}

// per-bucket prefix-scan of node degrees -> nodeoff[v] (edge start within elist)
__global__ __launch_bounds__(256) void bucket_scan(
    const int* __restrict__ nlist, const int* __restrict__ noff,
    const int* __restrict__ ncnt, const int* __restrict__ eoff,
    const int* __restrict__ ndeg, int* __restrict__ nodeoff) {
    int b = blockIdx.x;  // 0..19
    int start = noff[b];
    int cnt = ncnt[b];
    int ebase = eoff[b];
    __shared__ int sc[256];
    int tid = threadIdx.x;
    int carry = 0;
    for (int chunk = 0; chunk < cnt; chunk += 256) {
        __syncthreads();
        int i = chunk + tid;
        int v = -1, dg = 0;
        if (i < cnt) { v = nlist[start + i]; dg = ndeg[v]; }
        sc[tid] = dg;
        __syncthreads();
        for (int off = 1; off < 256; off <<= 1) {
            int y = (tid >= off) ? sc[tid - off] : 0;
            __syncthreads();
            sc[tid] += y;
            __syncthreads();
        }
        if (v >= 0) nodeoff[v] = ebase + carry + (sc[tid] - dg);
        carry += sc[255];
    }
}

// edges -> elist, dst-contiguous
__global__ void fill_edges(const int* __restrict__ dstA, const int* __restrict__ lev,
                           int E, const int* __restrict__ nodeoff,
                           int* __restrict__ ecur_n, int* __restrict__ elist) {
    int i = blockIdx.x * blockDim.x + threadIdx.x;
    if (i >= E) return;
    int d = dstA[i];
    int l = lev[d];
    if (l >= 1 && l < NLEV) {
        int pos = nodeoff[d] + atomicAdd(&ecur_n[d], 1);
        elist[pos] = i;
    }
}

// ================= MFMA edge pass (dst-grouped tiles; LDS pre-reduced atomics) =================
// 4 waves/block: (pass in {struct, func}) x (col-half hc).
// A-frag (16x16x32 bf16): lane l supplies A[l&15][(l>>4)*8 + j]
// B-frag: lane l supplies B[(l>>4)*8 + j][l&15]  -> contiguous in W^T[c][k]
// D: lane l holds out[(l>>4)*4 + reg][l&15] (m89-verified mapping)
__global__ __launch_bounds__(256) void edge_mfma(
    const ushortT* __restrict__ hsb, const ushortT* __restrict__ hfb,
    const ushortT* __restrict__ wt,
    const void* __restrict__ bs1, const void* __restrict__ bs2,
    const void* __restrict__ bf1, const void* __restrict__ bf2,
    const void* __restrict__ bnf1, const void* __restrict__ bnf2,
    const int* __restrict__ dstA, const int* __restrict__ srcA,
    const int* __restrict__ gate,
    const int* __restrict__ eoff, const int* __restrict__ elist,
    float* __restrict__ agg_s, float* __restrict__ agg_f, int level) {
    int lo = eoff[(level - 1) * 5];
    int hi = eoff[(level - 1) * 5 + 5];
    int base = lo + blockIdx.x * TE;
    if (base >= hi) return;

    __shared__ int se[TE], de[TE];
    __shared__ bf16 hid[2][16][136];      // 272B rows: 16B-aligned
    __shared__ float emsg[2][16][128];    // per-edge messages (+bias) for pre-reduction

    int tid = threadIdx.x;
    int wv = tid >> 6, pass = wv >> 1, hc = wv & 1, l = tid & 63;
    int lg = l >> 4, lr = l & 15;
    int isb = g_flag;

    int c = gate[dstA[elist[base]]];   // uniform over tile (buckets padded)
    int t = TMAP[c], fi = FMAP[c];

    if (tid < TE) {
        int e = elist[base + tid];
        se[tid] = (e < 0) ? -1 : srcA[e];
        de[tid] = (e < 0) ? -1 : dstA[e];
    }
    __syncthreads();

    int src = se[lr];   // A-operand row owned by this lane

    // ---- layer 1 ----
    int KS1; size_t wb1; int K1;
    if (pass == 0)      { KS1 = 4; wb1 = OFF_S1 + (size_t)t * 16384; K1 = 128; }
    else if (c == 2)    { KS1 = 4; wb1 = OFF_NF1; K1 = 128; }
    else                { KS1 = 8; wb1 = OFF_F1 + (size_t)fi * 32768; K1 = 256; }

    f32x4 a0 = {0.f,0.f,0.f,0.f}, a1 = a0, a2 = a0, a3 = a0;
    for (int ks = 0; ks < KS1; ++ks) {
        bf16x8 a = {0,0,0,0,0,0,0,0};
        if (src >= 0) {
            int kk = ks * 32 + lg * 8;
            const ushortT* ap;
            if (pass == 0)      ap = hsb + (size_t)src * D + kk;
            else if (c == 2)    ap = hfb + (size_t)src * D + kk;
            else                ap = (kk < 128) ? (hsb + (size_t)src * D + kk)
                                                : (hfb + (size_t)src * D + (kk - 128));
            a = *(const bf16x8*)ap;
        }
        int kb = ks * 32 + lg * 8;
        {
            bf16x8 b = *(const bf16x8*)&wt[wb1 + (size_t)(hc * 64 + 0 * 16 + lr) * K1 + kb];
            a0 = __builtin_amdgcn_mfma_f32_16x16x32_bf16(a, b, a0, 0, 0, 0);
        }
        {
            bf16x8 b = *(const bf16x8*)&wt[wb1 + (size_t)(hc * 64 + 1 * 16 + lr) * K1 + kb];
            a1 = __builtin_amdgcn_mfma_f32_16x16x32_bf16(a, b, a1, 0, 0, 0);
        }
        {
            bf16x8 b = *(const bf16x8*)&wt[wb1 + (size_t)(hc * 64 + 2 * 16 + lr) * K1 + kb];
            a2 = __builtin_amdgcn_mfma_f32_16x16x32_bf16(a, b, a2, 0, 0, 0);
        }
        {
            bf16x8 b = *(const bf16x8*)&wt[wb1 + (size_t)(hc * 64 + 3 * 16 + lr) * K1 + kb];
            a3 = __builtin_amdgcn_mfma_f32_16x16x32_bf16(a, b, a3, 0, 0, 0);
        }
    }

    // bias + relu -> bf16 hidden in LDS
    const void* b1p = (pass == 0) ? bs1 : (c == 2 ? bnf1 : bf1);
    size_t b1o = (pass == 0) ? (size_t)t * D : (c == 2 ? 0 : (size_t)fi * D);
    {
        f32x4 av[4] = { a0, a1, a2, a3 };
#pragma unroll
        for (int ct = 0; ct < 4; ++ct) {
            int cc = hc * 64 + ct * 16 + lr;
            float bb = isb ? ld<1>(b1p, b1o + cc) : ld<0>(b1p, b1o + cc);
#pragma unroll
            for (int r = 0; r < 4; ++r) {
                int m = lg * 4 + r;
                float v = fmaxf(av[ct][r] + bb, 0.f);
                hid[pass][m][cc] = __float2bfloat16(v);
            }
        }
    }
    __syncthreads();

    // ---- layer 2 (K=128 over hidden) ----
    size_t wb2 = (pass == 0) ? (OFF_S2 + (size_t)t * 16384)
                             : (c == 2 ? (size_t)OFF_NF2 : (OFF_F2 + (size_t)fi * 16384));
    a0 = (f32x4){0.f,0.f,0.f,0.f}; a1 = a0; a2 = a0; a3 = a0;
#pragma unroll
    for (int ks = 0; ks < 4; ++ks) {
        bf16x8 a = *(const bf16x8*)&hid[pass][lr][ks * 32 + lg * 8];
        int kb = ks * 32 + lg * 8;
        {
            bf16x8 b = *(const bf16x8*)&wt[wb2 + (size_t)(hc * 64 + 0 * 16 + lr) * 128 + kb];
            a0 = __builtin_amdgcn_mfma_f32_16x16x32_bf16(a, b, a0, 0, 0, 0);
        }
        {
            bf16x8 b = *(const bf16x8*)&wt[wb2 + (size_t)(hc * 64 + 1 * 16 + lr) * 128 + kb];
            a1 = __builtin_amdgcn_mfma_f32_16x16x32_bf16(a, b, a1, 0, 0, 0);
        }
        {
            bf16x8 b = *(const bf16x8*)&wt[wb2 + (size_t)(hc * 64 + 2 * 16 + lr) * 128 + kb];
            a2 = __builtin_amdgcn_mfma_f32_16x16x32_bf16(a, b, a2, 0, 0, 0);
        }
        {
            bf16x8 b = *(const bf16x8*)&wt[wb2 + (size_t)(hc * 64 + 3 * 16 + lr) * 128 + kb];
            a3 = __builtin_amdgcn_mfma_f32_16x16x32_bf16(a, b, a3, 0, 0, 0);
        }
    }

    // per-edge bias folded in, stash to LDS for same-dst pre-reduction
    const void* b2p = (pass == 0) ? bs2 : (c == 2 ? bnf2 : bf2);
    size_t b2o = (pass == 0) ? (size_t)t * D : (c == 2 ? 0 : (size_t)fi * D);
    {
        f32x4 av[4] = { a0, a1, a2, a3 };
#pragma unroll
        for (int ct = 0; ct < 4; ++ct) {
            int cc = hc * 64 + ct * 16 + lr;
            float bb = isb ? ld<1>(b2p, b2o + cc) : ld<0>(b2p, b2o + cc);
#pragma unroll
            for (int r = 0; r < 4; ++r) {
                int m = lg * 4 + r;
                emsg[pass][m][cc] = av[ct][r] + bb;
            }
        }
    }
    __syncthreads();

    // run-detect on de[] (dst-grouped): one atomic per distinct dst per col
    float* aggp = pass ? agg_f : agg_s;
    int col = hc * 64 + l;
    float s = 0.f;
    for (int m = 0; m < TE; ++m) {
        int d = de[m];
        if (d < 0) break;                 // padding is contiguous at tile end
        s += emsg[pass][m][col];
        bool flush = (m == TE - 1) || (de[m + 1] != d);
        if (flush) {
            atomicAdd(&aggp[(size_t)d * D + col], s);
            s = 0.f;
        }
    }
}

// ===== fused node GRU: GEMM partials (12 waves) -> LDS -> nonlinearity, no gtmp =====
template <int ISB, int MC, int R>
__device__ __forceinline__ void mmB(
    const float (&x0)[R], const float (&x1)[R],
    const void* __restrict__ W, size_t wofs, int wstride,
    int mstart, int c0, float (&out)[R][2]) {
#pragma unroll 4
    for (int mm = 0; mm < MC; ++mm) {
        int m = mstart + mm;
        float2 w0 = ld2<ISB>(W, wofs + (size_t)(2 * m) * wstride + c0);
        float2 w1 = ld2<ISB>(W, wofs + (size_t)(2 * m + 1) * wstride + c0);
#pragma unroll
        for (int r = 0; r < R; ++r) {
            float xa = rlane(x0[r], m);
            float xb = rlane(x1[r], m);
            out[r][0] = fmaf(xb, w1.x, fmaf(xa, w0.x, out[r][0]));
            out[r][1] = fmaf(xb, w1.y, fmaf(xa, w0.y, out[r][1]));
        }
    }
}

template <int ISB>
__device__ void node_fused_body(
    const float* __restrict__ agg_s, const float* __restrict__ agg_f,
    const void* __restrict__ Gs_wih, const void* __restrict__ Gf_wih,
    const void* __restrict__ Gs_bih, const void* __restrict__ Gs_bhh,
    const void* __restrict__ Gf_bih, const void* __restrict__ Gf_bhh,
    float* __restrict__ hs, float* __restrict__ hf,
    ushortT* __restrict__ hsb, ushortT* __restrict__ hfb,
    const int* __restrict__ gate,
    const int* __restrict__ noff, const int* __restrict__ nlist,
    int level, float (*gi)[3][16][128]) {
    int lo = noff[(level - 1) * 5];
    int hi = noff[(level - 1) * 5 + 5];
    int base = lo + blockIdx.x * TN;
    if (base >= hi) return;
    int tid = threadIdx.x;
    int w = tid >> 6, l = tid & 63;
    int p = w / 6, r6 = w % 6, gg = r6 >> 1, rh = r6 & 1;
    int c0 = 2 * l;
    int t = TMAP[gate[nlist[base]]];

    const float* agg = p ? agg_f : agg_s;
    const void* wih = p ? Gf_wih : Gs_wih;

    float x0[8], x1[8];
#pragma unroll
    for (int r = 0; r < 8; ++r) {
        int v = nlist[base + rh * 8 + r];
        float2 a = (v >= 0) ? *(const float2*)&agg[(size_t)v * D + c0]
                            : make_float2(0.f, 0.f);
        x0[r] = a.x; x1[r] = a.y;
    }
    float acc[8][2];
#pragma unroll
    for (int r = 0; r < 8; ++r) { acc[r][0] = 0.f; acc[r][1] = 0.f; }
    mmB<ISB, 64, 8>(x0, x1, wih, (size_t)t * D * 3 * D, 3 * D, 0, gg * 128 + c0, acc);
#pragma unroll
    for (int r = 0; r < 8; ++r) {
        gi[p][gg][rh * 8 + r][c0] = acc[r][0];
        gi[p][gg][rh * 8 + r][c0 + 1] = acc[r][1];
    }
    __syncthreads();

    if (tid < 256) {
        int pp = tid >> 7, j = tid & 127;
        const void* bih = pp ? Gf_bih : Gs_bih;
        const void* bhh = pp ? Gf_bhh : Gs_bhh;
        float br = ld<ISB>(bih, (size_t)t * 384 + j);
        float bz = ld<ISB>(bih, (size_t)t * 384 + 128 + j);
        float bn = ld<ISB>(bih, (size_t)t * 384 + 256 + j);
        float hr = ld<ISB>(bhh, (size_t)t * 384 + j);
        float hz = ld<ISB>(bhh, (size_t)t * 384 + 128 + j);
        float hn = ld<ISB>(bhh, (size_t)t * 384 + 256 + j);
        float* ho = pp ? hf : hs;
        ushortT* hb = pp ? hfb : hsb;
#pragma unroll
        for (int r = 0; r < TN; ++r) {
            int v = nlist[base + r];
            if (v < 0) continue;
            float rr = sigm(gi[pp][0][r][j] + br + hr);
            float z = sigm(gi[pp][1][r][j] + bz + hz);
            float n = tanhf(gi[pp][2][r][j] + bn + rr * hn);
            float out = (1.f - z) * n;
            ho[(size_t)v * D + j] = out;
            hb[(size_t)v * D + j] = f2b(out);
        }
    }
}

__global__ __launch_bounds__(768) void node_fused(
    const float* agg_s, const float* agg_f,
    const void* Gs_wih, const void* Gf_wih,
    const void* Gs_bih, const void* Gs_bhh,
    const void* Gf_bih, const void* Gf_bhh,
    float* hs, float* hf, ushortT* hsb, ushortT* hfb,
    const int* gate, const int* noff, const int* nlist, int level) {
    __shared__ float gi[2][3][16][128];
    if (g_flag)
        node_fused_body<1>(agg_s, agg_f, Gs_wih, Gf_wih, Gs_bih, Gs_bhh,
                           Gf_bih, Gf_bhh, hs, hf, hsb, hfb, gate, noff, nlist,
                           level, gi);
    else
        node_fused_body<0>(agg_s, agg_f, Gs_wih, Gf_wih, Gs_bih, Gs_bhh,
                           Gf_bih, Gf_bhh, hs, hf, hsb, hfb, gate, noff, nlist,
                           level, gi);
}

// ---------------- writeout: from f32 canonical ----------------
__global__ void writeout(const float* __restrict__ hs, const float* __restrict__ hf,
                         void* __restrict__ out, int ND) {
    int i = blockIdx.x * blockDim.x + threadIdx.x;
    if (i >= ND) return;
    if (g_flag) {
        ((ushortT*)out)[i] = f2b(hs[i]);
        ((ushortT*)out)[ND + i] = f2b(hf[i]);
    } else {
        ((float*)out)[i] = hs[i];
        ((float*)out)[ND + i] = hf[i];
    }
}

extern "C" void kernel_launch(void* const* d_in, const int* in_sizes, int n_in,
                              void* d_out, int out_size, void* d_ws, size_t ws_size,
                              hipStream_t stream) {
    const void* hs_init = d_in[0];
    const void* Ws1 = d_in[1];
    const void* bs1 = d_in[2];
    const void* Ws2 = d_in[3];
    const void* bs2 = d_in[4];
    const void* Wf1 = d_in[5];
    const void* bf1 = d_in[6];
    const void* Wf2 = d_in[7];
    const void* bf2 = d_in[8];
    const void* Wnf1 = d_in[9];
    const void* bnf1 = d_in[10];
    const void* Wnf2 = d_in[11];
    const void* bnf2 = d_in[12];
    const void* Gs_wih = d_in[13];
    const void* Gs_bih = d_in[15];
    const void* Gs_bhh = d_in[16];
    const void* Gf_wih = d_in[17];
    const void* Gf_bih = d_in[19];
    const void* Gf_bhh = d_in[20];
    const int* edge_index = (const int*)d_in[21];
    const int* gate = (const int*)d_in[22];
    const int* lev = (const int*)d_in[23];

    int E = in_sizes[21] / 2;
    int N = in_sizes[22];
    int ND = N * D;
    int cap = ((N / NLEV + 5 * TN + 64) + TN - 1) / TN * TN;

    float* hs = (float*)d_ws;
    float* hf = hs + ND;
    float* agg_s = hf + ND;
    float* agg_f = agg_s + ND;
    ushortT* hsb = (ushortT*)(agg_f + ND);           // ND ushorts
    ushortT* hfb = hsb + ND;
    ushortT* wt = hfb + ND;                          // WT_TOTAL ushorts
    int* meta = (int*)(wt + WT_TOTAL);
    int* ecnt = meta;            // 20
    int* ncnt = ecnt + 20;       // 20
    int* ncur = ncnt + 20;       // 20
    int* eoff = ncur + 20;       // 21
    int* noff = eoff + 21;       // 21  (meta total 102; pad to 128)
    int* ndeg = meta + 128;      // N
    int* ecur_n = ndeg + N;      // N
    int* nodeoff = ecur_n + N;   // N
    int* elist = nodeoff + N;    // E + 20*TE
    int* nlist = elist + (E + 20 * TE);  // N + 20*TN

    const int* srcA = edge_index;
    const int* dstA = edge_index + E;

    detect_dtype<<<1, 64, 0, stream>>>(hs_init);
    hipMemsetAsync(agg_s, 0, (size_t)2 * ND * sizeof(float), stream);
    hipMemsetAsync(meta, 0, (size_t)(128 + 2 * N) * sizeof(int), stream);  // meta+ndeg+ecur_n
    hipMemsetAsync(elist, 0xFF, (size_t)(E + 20 * TE + N + 20 * TN) * sizeof(int), stream);
    init_state<<<N, D, 0, stream>>>(hs_init, gate, hs, hf, hsb, hfb);

    // weight transposes + bf16 conversion
    transpose_w<<<dim3(128, 5), 128, 0, stream>>>(Ws1, wt + OFF_S1, 128, 128);
    transpose_w<<<dim3(128, 5), 128, 0, stream>>>(Ws2, wt + OFF_S2, 128, 128);
    transpose_w<<<dim3(128, 4), 256, 0, stream>>>(Wf1, wt + OFF_F1, 256, 128);
    transpose_w<<<dim3(128, 4), 128, 0, stream>>>(Wf2, wt + OFF_F2, 128, 128);
    transpose_w<<<dim3(128, 1), 128, 0, stream>>>(Wnf1, wt + OFF_NF1, 128, 128);
    transpose_w<<<dim3(128, 1), 128, 0, stream>>>(Wnf2, wt + OFF_NF2, 128, 128);

    int mx = (E > N) ? E : N;
    count_bins<<<(mx + 255) / 256, 256, 0, stream>>>(dstA, gate, lev, E, N, ecnt, ncnt, ndeg);
    scan_offsets<<<1, 64, 0, stream>>>(ecnt, ncnt, eoff, noff);
    fill_bins<<<(N + 255) / 256, 256, 0, stream>>>(gate, lev, N, noff, ncur, nlist);
    bucket_scan<<<20, 256, 0, stream>>>(nlist, noff, ncnt, eoff, ndeg, nodeoff);
    fill_edges<<<(E + 255) / 256, 256, 0, stream>>>(dstA, lev, E, nodeoff, ecur_n, elist);

    int gridE = (E + 20 * TE) / TE + 1;
    int gridNcap = cap / TN;
    for (int level = 1; level < NLEV; ++level) {
        edge_mfma<<<gridE, 256, 0, stream>>>(hsb, hfb, wt,
                                             bs1, bs2, bf1, bf2, bnf1, bnf2,
                                             dstA, srcA, gate, eoff, elist,
                                             agg_s, agg_f, level);
        node_fused<<<gridNcap, 768, 0, stream>>>(agg_s, agg_f, Gs_wih, Gf_wih,
                                                 Gs_bih, Gs_bhh, Gf_bih, Gf_bhh,
                                                 hs, hf, hsb, hfb,
                                                 gate, noff, nlist, level);
    }

    writeout<<<(ND + 255) / 256, 256, 0, stream>>>(hs, hf, d_out, ND);
}

// Round 11
// 267.519 us; speedup vs baseline: 2.3062x; 1.1297x over previous
//
#include <hip/hip_runtime.h>
#include <hip/hip_bf16.h>

typedef __hip_bfloat16 bf16;
typedef unsigned short ushortT;
typedef __attribute__((ext_vector_type(8))) short bf16x8;
typedef __attribute__((ext_vector_type(4))) float f32x4;

#define D 128
#define NLEV 5
#define TE 16  // edges per tile (MFMA M=16)
#define TN 16  // nodes per tile

// weight blob element offsets (bf16 elements), all stored transposed [C][K]
#define OFF_S1 0          // [5][128][128]
#define OFF_S2 81920      // [5][128][128]
#define OFF_F1 163840     // [4][128][256]
#define OFF_F2 294912     // [4][128][128]
#define OFF_NF1 360448    // [128][128]
#define OFF_NF2 376832    // [128][128]
#define OFF_GSH 393216    // [5][384][128] Gs_wih hi
#define OFF_GFH 638976    // [5][384][128] Gf_wih hi
#define OFF_GSL 884736    // [5][384][128] Gs_wih lo
#define OFF_GFL 1130496   // [5][384][128] Gf_wih lo
#define WT_TOTAL 1376256

// gate code -> t (enumerate index in CODES=[3,2,5,1,4]); index 0 unused
__constant__ int TMAP[6] = { -1, 3, 1, 0, 4, 2 };
// gate code -> func-aggregator index (FIDX={3:0,5:1,1:2,4:3}); codes 0,2 unused
__constant__ int FMAP[6] = { -1, 2, -1, 0, 3, 1 };

// dtype flag: 1 = float tensors stored as bf16, 0 = stored as float32
__device__ int g_flag;

__device__ __forceinline__ float sigm(float x) { return 1.0f / (1.0f + __expf(-x)); }

__device__ __forceinline__ ushortT f2b(float v) {
    bf16 h = __float2bfloat16(v);
    return *reinterpret_cast<ushortT*>(&h);
}

template <int ISB>
__device__ __forceinline__ float ld(const void* p, size_t i) {
    if (ISB) return __bfloat162float(((const bf16*)p)[i]);
    return ((const float*)p)[i];
}

// ---- dtype sniffer ----
__global__ void detect_dtype(const void* hs_init) {
    int t = threadIdx.x;
    float x = __bfloat162float(((const bf16*)hs_init)[2 * t]);
    float ax = fabsf(x);
    bool sane = (x == 0.0f) || (ax > 1e-4f && ax < 64.0f);
    unsigned long long m = __ballot(sane);
    if (t == 0) g_flag = (__popcll(m) >= 32) ? 1 : 0;
}

// ---- init: f32 canonical states + bf16 mirrors ----
__global__ void init_state(const void* __restrict__ hs_init,
                           const int* __restrict__ gate,
                           float* __restrict__ hs, float* __restrict__ hf,
                           ushortT* __restrict__ hsb, ushortT* __restrict__ hfb) {
    int v = blockIdx.x;
    int j = threadIdx.x;
    size_t idx = (size_t)v * D + j;
    bool pi = (gate[v] == 0);
    float val = 0.f;
    ushortT bval = 0;
    if (pi) {
        if (g_flag) {
            bval = ((const ushortT*)hs_init)[idx];
            bf16 h = *reinterpret_cast<bf16*>(&bval);
            val = __bfloat162float(h);
        } else {
            val = ((const float*)hs_init)[idx];
            bval = f2b(val);
        }
    }
    hs[idx] = val; hf[idx] = 0.f;
    hsb[idx] = bval; hfb[idx] = 0;
}

// ---- fused weight prep: all transposes + bf16 convert + GRU hi/lo split ----
__global__ void prep_weights(const void* __restrict__ Ws1, const void* __restrict__ Ws2,
                             const void* __restrict__ Wf1, const void* __restrict__ Wf2,
                             const void* __restrict__ Wnf1, const void* __restrict__ Wnf2,
                             const void* __restrict__ Gs, const void* __restrict__ Gf,
                             ushortT* __restrict__ wt) {
    int i = blockIdx.x * blockDim.x + threadIdx.x;
    if (i >= WT_TOTAL) return;
    const void* src; int Kd, C, rem, mode = 0;  // mode 0: plain, 1: hi, 2: lo
    if (i < OFF_S2)       { src = Ws1;  rem = i;           Kd = 128; C = 128; }
    else if (i < OFF_F1)  { src = Ws2;  rem = i - OFF_S2;  Kd = 128; C = 128; }
    else if (i < OFF_F2)  { src = Wf1;  rem = i - OFF_F1;  Kd = 256; C = 128; }
    else if (i < OFF_NF1) { src = Wf2;  rem = i - OFF_F2;  Kd = 128; C = 128; }
    else if (i < OFF_NF2) { src = Wnf1; rem = i - OFF_NF1; Kd = 128; C = 128; }
    else if (i < OFF_GSH) { src = Wnf2; rem = i - OFF_NF2; Kd = 128; C = 128; }
    else if (i < OFF_GFH) { src = Gs;   rem = i - OFF_GSH; Kd = 128; C = 384; mode = 1; }
    else if (i < OFF_GSL) { src = Gf;   rem = i - OFF_GFH; Kd = 128; C = 384; mode = 1; }
    else if (i < OFF_GFL) { src = Gs;   rem = i - OFF_GSL; Kd = 128; C = 384; mode = 2; }
    else                  { src = Gf;   rem = i - OFF_GFL; Kd = 128; C = 384; mode = 2; }
    int n = rem / (Kd * C);
    int r2 = rem % (Kd * C);
    int c = r2 / Kd;
    int k = r2 % Kd;
    size_t si = (size_t)n * Kd * C + (size_t)k * C + c;
    float v = g_flag ? ld<1>(src, si) : ld<0>(src, si);
    ushortT out;
    if (mode == 2) {
        bf16 h = __float2bfloat16(v);
        out = f2b(v - __bfloat162float(h));   // lo residue (0 when src is bf16)
    } else {
        out = f2b(v);
    }
    wt[i] = out;
}

// ========== bucketing: (level-1)*5 + t, levels 1..4; edges dst-grouped ==========
__global__ void count_bins(const int* __restrict__ dstA, const int* __restrict__ gate,
                           const int* __restrict__ lev, int E, int N,
                           int* __restrict__ ecnt, int* __restrict__ ncnt,
                           int* __restrict__ ndeg) {
    __shared__ int lc[40];
    int tid = threadIdx.x;
    if (tid < 40) lc[tid] = 0;
    __syncthreads();
    int i = blockIdx.x * blockDim.x + tid;
    if (i < E) {
        int d = dstA[i]; int l = lev[d];
        if (l >= 1 && l < NLEV) {
            atomicAdd(&lc[(l - 1) * 5 + TMAP[gate[d]]], 1);
            atomicAdd(&ndeg[d], 1);
        }
    }
    if (i < N) {
        int l = lev[i];
        if (l >= 1 && l < NLEV && gate[i] >= 1) atomicAdd(&lc[20 + (l - 1) * 5 + TMAP[gate[i]]], 1);
    }
    __syncthreads();
    if (tid < 20 && lc[tid]) atomicAdd(&ecnt[tid], lc[tid]);
    if (tid >= 20 && tid < 40 && lc[tid]) atomicAdd(&ncnt[tid - 20], lc[tid]);
}

__global__ void scan_offsets(const int* __restrict__ ecnt, const int* __restrict__ ncnt,
                             int* __restrict__ eoff, int* __restrict__ noff) {
    if (threadIdx.x == 0 && blockIdx.x == 0) {
        int o = 0;
        for (int b = 0; b < 20; ++b) { eoff[b] = o; o += ((ecnt[b] + TE - 1) / TE) * TE; }
        eoff[20] = o;
        o = 0;
        for (int b = 0; b < 20; ++b) { noff[b] = o; o += ((ncnt[b] + TN - 1) / TN) * TN; }
        noff[20] = o;
    }
}

// nodes -> nlist (bucketed, padded with -1)
__global__ void fill_bins(const int* __restrict__ gate, const int* __restrict__ lev, int N,
                          const int* __restrict__ noff, int* __restrict__ ncur,
                          int* __restrict__ nlist) {
    __shared__ int nc[20], nb[20];
    int tid = threadIdx.x;
    if (tid < 20) nc[tid] = 0;
    __syncthreads();
    int i = blockIdx.x * blockDim.x + tid;
    int bn = -1, rn = 0;
    if (i < N) {
        int l = lev[i];
        if (l >= 1 && l < NLEV && gate[i] >= 1) { bn = (l - 1) * 5 + TMAP[gate[i]]; rn = atomicAdd(&nc[bn], 1); }
    }
    __syncthreads();
    if (tid < 20) nb[tid] = nc[tid] ? atomicAdd(&ncur[tid], nc[tid]) : 0;
    __syncthreads();
    if (bn >= 0) nlist[noff[bn] + nb[bn] + rn] = i;
}

// per-bucket prefix-scan of node degrees -> nodeoff[v] (edge start within elist)
__global__ __launch_bounds__(256) void bucket_scan(
    const int* __restrict__ nlist, const int* __restrict__ noff,
    const int* __restrict__ ncnt, const int* __restrict__ eoff,
    const int* __restrict__ ndeg, int* __restrict__ nodeoff) {
    int b = blockIdx.x;  // 0..19
    int start = noff[b];
    int cnt = ncnt[b];
    int ebase = eoff[b];
    __shared__ int sc[256];
    int tid = threadIdx.x;
    int carry = 0;
    for (int chunk = 0; chunk < cnt; chunk += 256) {
        __syncthreads();
        int i = chunk + tid;
        int v = -1, dg = 0;
        if (i < cnt) { v = nlist[start + i]; dg = ndeg[v]; }
        sc[tid] = dg;
        __syncthreads();
        for (int off = 1; off < 256; off <<= 1) {
            int y = (tid >= off) ? sc[tid - off] : 0;
            __syncthreads();
            sc[tid] += y;
            __syncthreads();
        }
        if (v >= 0) nodeoff[v] = ebase + carry + (sc[tid] - dg);
        carry += sc[255];
    }
}

// edges -> elist, dst-contiguous
__global__ void fill_edges(const int* __restrict__ dstA, const int* __restrict__ lev,
                           int E, const int* __restrict__ nodeoff,
                           int* __restrict__ ecur_n, int* __restrict__ elist) {
    int i = blockIdx.x * blockDim.x + threadIdx.x;
    if (i >= E) return;
    int d = dstA[i];
    int l = lev[d];
    if (l >= 1 && l < NLEV) {
        int pos = nodeoff[d] + atomicAdd(&ecur_n[d], 1);
        elist[pos] = i;
    }
}

// ================= MFMA edge pass (dst-grouped tiles; LDS pre-reduced atomics) =================
// 4 waves/block: (pass in {struct, func}) x (col-half hc).
// A-frag (16x16x32 bf16): lane l supplies A[l&15][(l>>4)*8 + j]
// B-frag: lane l supplies B[(l>>4)*8 + j][l&15]  -> contiguous in W^T[c][k]
// D: lane l holds out[(l>>4)*4 + reg][l&15] (m89-verified mapping)
__global__ __launch_bounds__(256) void edge_mfma(
    const ushortT* __restrict__ hsb, const ushortT* __restrict__ hfb,
    const ushortT* __restrict__ wt,
    const void* __restrict__ bs1, const void* __restrict__ bs2,
    const void* __restrict__ bf1, const void* __restrict__ bf2,
    const void* __restrict__ bnf1, const void* __restrict__ bnf2,
    const int* __restrict__ dstA, const int* __restrict__ srcA,
    const int* __restrict__ gate,
    const int* __restrict__ eoff, const int* __restrict__ elist,
    float* __restrict__ agg_s, float* __restrict__ agg_f, int level) {
    int lo = eoff[(level - 1) * 5];
    int hi = eoff[(level - 1) * 5 + 5];
    int base = lo + blockIdx.x * TE;
    if (base >= hi) return;

    __shared__ int se[TE], de[TE];
    __shared__ bf16 hid[2][16][136];      // 272B rows: 16B-aligned
    __shared__ float emsg[2][16][128];    // per-edge messages (+bias) for pre-reduction

    int tid = threadIdx.x;
    int wv = tid >> 6, pass = wv >> 1, hc = wv & 1, l = tid & 63;
    int lg = l >> 4, lr = l & 15;
    int isb = g_flag;

    int c = gate[dstA[elist[base]]];   // uniform over tile (buckets padded)
    int t = TMAP[c], fi = FMAP[c];

    if (tid < TE) {
        int e = elist[base + tid];
        se[tid] = (e < 0) ? -1 : srcA[e];
        de[tid] = (e < 0) ? -1 : dstA[e];
    }
    __syncthreads();

    int src = se[lr];   // A-operand row owned by this lane

    // ---- layer 1 ----
    int KS1; size_t wb1; int K1;
    if (pass == 0)      { KS1 = 4; wb1 = OFF_S1 + (size_t)t * 16384; K1 = 128; }
    else if (c == 2)    { KS1 = 4; wb1 = OFF_NF1; K1 = 128; }
    else                { KS1 = 8; wb1 = OFF_F1 + (size_t)fi * 32768; K1 = 256; }

    f32x4 a0 = {0.f,0.f,0.f,0.f}, a1 = a0, a2 = a0, a3 = a0;
    for (int ks = 0; ks < KS1; ++ks) {
        bf16x8 a = {0,0,0,0,0,0,0,0};
        if (src >= 0) {
            int kk = ks * 32 + lg * 8;
            const ushortT* ap;
            if (pass == 0)      ap = hsb + (size_t)src * D + kk;
            else if (c == 2)    ap = hfb + (size_t)src * D + kk;
            else                ap = (kk < 128) ? (hsb + (size_t)src * D + kk)
                                                : (hfb + (size_t)src * D + (kk - 128));
            a = *(const bf16x8*)ap;
        }
        int kb = ks * 32 + lg * 8;
        {
            bf16x8 b = *(const bf16x8*)&wt[wb1 + (size_t)(hc * 64 + 0 * 16 + lr) * K1 + kb];
            a0 = __builtin_amdgcn_mfma_f32_16x16x32_bf16(a, b, a0, 0, 0, 0);
        }
        {
            bf16x8 b = *(const bf16x8*)&wt[wb1 + (size_t)(hc * 64 + 1 * 16 + lr) * K1 + kb];
            a1 = __builtin_amdgcn_mfma_f32_16x16x32_bf16(a, b, a1, 0, 0, 0);
        }
        {
            bf16x8 b = *(const bf16x8*)&wt[wb1 + (size_t)(hc * 64 + 2 * 16 + lr) * K1 + kb];
            a2 = __builtin_amdgcn_mfma_f32_16x16x32_bf16(a, b, a2, 0, 0, 0);
        }
        {
            bf16x8 b = *(const bf16x8*)&wt[wb1 + (size_t)(hc * 64 + 3 * 16 + lr) * K1 + kb];
            a3 = __builtin_amdgcn_mfma_f32_16x16x32_bf16(a, b, a3, 0, 0, 0);
        }
    }

    // bias + relu -> bf16 hidden in LDS
    const void* b1p = (pass == 0) ? bs1 : (c == 2 ? bnf1 : bf1);
    size_t b1o = (pass == 0) ? (size_t)t * D : (c == 2 ? 0 : (size_t)fi * D);
    {
        f32x4 av[4] = { a0, a1, a2, a3 };
#pragma unroll
        for (int ct = 0; ct < 4; ++ct) {
            int cc = hc * 64 + ct * 16 + lr;
            float bb = isb ? ld<1>(b1p, b1o + cc) : ld<0>(b1p, b1o + cc);
#pragma unroll
            for (int r = 0; r < 4; ++r) {
                int m = lg * 4 + r;
                float v = fmaxf(av[ct][r] + bb, 0.f);
                hid[pass][m][cc] = __float2bfloat16(v);
            }
        }
    }
    __syncthreads();

    // ---- layer 2 (K=128 over hidden) ----
    size_t wb2 = (pass == 0) ? (OFF_S2 + (size_t)t * 16384)
                             : (c == 2 ? (size_t)OFF_NF2 : (OFF_F2 + (size_t)fi * 16384));
    a0 = (f32x4){0.f,0.f,0.f,0.f}; a1 = a0; a2 = a0; a3 = a0;
#pragma unroll
    for (int ks = 0; ks < 4; ++ks) {
        bf16x8 a = *(const bf16x8*)&hid[pass][lr][ks * 32 + lg * 8];
        int kb = ks * 32 + lg * 8;
        {
            bf16x8 b = *(const bf16x8*)&wt[wb2 + (size_t)(hc * 64 + 0 * 16 + lr) * 128 + kb];
            a0 = __builtin_amdgcn_mfma_f32_16x16x32_bf16(a, b, a0, 0, 0, 0);
        }
        {
            bf16x8 b = *(const bf16x8*)&wt[wb2 + (size_t)(hc * 64 + 1 * 16 + lr) * 128 + kb];
            a1 = __builtin_amdgcn_mfma_f32_16x16x32_bf16(a, b, a1, 0, 0, 0);
        }
        {
            bf16x8 b = *(const bf16x8*)&wt[wb2 + (size_t)(hc * 64 + 2 * 16 + lr) * 128 + kb];
            a2 = __builtin_amdgcn_mfma_f32_16x16x32_bf16(a, b, a2, 0, 0, 0);
        }
        {
            bf16x8 b = *(const bf16x8*)&wt[wb2 + (size_t)(hc * 64 + 3 * 16 + lr) * 128 + kb];
            a3 = __builtin_amdgcn_mfma_f32_16x16x32_bf16(a, b, a3, 0, 0, 0);
        }
    }

    // per-edge bias folded in, stash to LDS for same-dst pre-reduction
    const void* b2p = (pass == 0) ? bs2 : (c == 2 ? bnf2 : bf2);
    size_t b2o = (pass == 0) ? (size_t)t * D : (c == 2 ? 0 : (size_t)fi * D);
    {
        f32x4 av[4] = { a0, a1, a2, a3 };
#pragma unroll
        for (int ct = 0; ct < 4; ++ct) {
            int cc = hc * 64 + ct * 16 + lr;
            float bb = isb ? ld<1>(b2p, b2o + cc) : ld<0>(b2p, b2o + cc);
#pragma unroll
            for (int r = 0; r < 4; ++r) {
                int m = lg * 4 + r;
                emsg[pass][m][cc] = av[ct][r] + bb;
            }
        }
    }
    __syncthreads();

    // run-detect on de[] (dst-grouped): one atomic per distinct dst per col
    float* aggp = pass ? agg_f : agg_s;
    int col = hc * 64 + l;
    float s = 0.f;
    for (int m = 0; m < TE; ++m) {
        int d = de[m];
        if (d < 0) break;                 // padding is contiguous at tile end
        s += emsg[pass][m][col];
        bool flush = (m == TE - 1) || (de[m + 1] != d);
        if (flush) {
            atomicAdd(&aggp[(size_t)d * D + col], s);
            s = 0.f;
        }
    }
}

// ===== fused node GRU: MFMA gi (hi/lo compensated) -> LDS -> nonlinearity =====
// 12 waves: wave w -> p = w/6, colgroup cg = w%6 (4 col-tiles of 16 each).
template <int ISB>
__device__ void node_fused_body(
    const float* __restrict__ agg_s, const float* __restrict__ agg_f,
    const ushortT* __restrict__ wt,
    const void* __restrict__ Gs_bih, const void* __restrict__ Gs_bhh,
    const void* __restrict__ Gf_bih, const void* __restrict__ Gf_bhh,
    float* __restrict__ hs, float* __restrict__ hf,
    ushortT* __restrict__ hsb, ushortT* __restrict__ hfb,
    const int* __restrict__ gate,
    const int* __restrict__ noff, const int* __restrict__ nlist,
    int level, float (*gi)[3][16][128]) {
    int lo = noff[(level - 1) * 5];
    int hi = noff[(level - 1) * 5 + 5];
    int base = lo + blockIdx.x * TN;
    if (base >= hi) return;
    int tid = threadIdx.x;
    int w = tid >> 6, l = tid & 63;
    int lg = l >> 4, lr = l & 15;
    int p = w / 6, cg = w % 6;
    int t = TMAP[gate[nlist[base]]];

    const float* agg = p ? agg_f : agg_s;
    size_t wbh = (p ? OFF_GFH : OFF_GSH) + (size_t)t * 49152;
    size_t wbl = (p ? OFF_GFL : OFF_GSL) + (size_t)t * 49152;

    int v = nlist[base + lr];   // A-operand row owned by this lane

    f32x4 acc[4];
#pragma unroll
    for (int q = 0; q < 4; ++q) acc[q] = (f32x4){0.f, 0.f, 0.f, 0.f};

    for (int ks = 0; ks < 4; ++ks) {
        bf16x8 ahi = {0,0,0,0,0,0,0,0}, alo = ahi;
        if (v >= 0) {
            const float* ap = agg + (size_t)v * D + ks * 32 + lg * 8;
            float4 f0 = *(const float4*)ap;
            float4 f1 = *(const float4*)(ap + 4);
            float av[8] = { f0.x, f0.y, f0.z, f0.w, f1.x, f1.y, f1.z, f1.w };
#pragma unroll
            for (int j = 0; j < 8; ++j) {
                bf16 h = __float2bfloat16(av[j]);
                ahi[j] = (short)*reinterpret_cast<ushortT*>(&h);
                float r = av[j] - __bfloat162float(h);
                bf16 l2 = __float2bfloat16(r);
                alo[j] = (short)*reinterpret_cast<ushortT*>(&l2);
            }
        }
        int kb = ks * 32 + lg * 8;
#pragma unroll
        for (int q = 0; q < 4; ++q) {
            int col = (cg * 4 + q) * 16 + lr;
            bf16x8 bh = *(const bf16x8*)&wt[wbh + (size_t)col * 128 + kb];
            acc[q] = __builtin_amdgcn_mfma_f32_16x16x32_bf16(ahi, bh, acc[q], 0, 0, 0);
            acc[q] = __builtin_amdgcn_mfma_f32_16x16x32_bf16(alo, bh, acc[q], 0, 0, 0);
            if (!ISB) {   // f32 weights: add hi*lo correction (lo=0 when src bf16)
                bf16x8 bl = *(const bf16x8*)&wt[wbl + (size_t)col * 128 + kb];
                acc[q] = __builtin_amdgcn_mfma_f32_16x16x32_bf16(ahi, bl, acc[q], 0, 0, 0);
            }
        }
    }

#pragma unroll
    for (int q = 0; q < 4; ++q) {
        int ct = cg * 4 + q;
        int g = ct >> 3, j = (ct & 7) * 16 + lr;
#pragma unroll
        for (int r = 0; r < 4; ++r) gi[p][g][lg * 4 + r][j] = acc[q][r];
    }
    __syncthreads();

    if (tid < 256) {
        int pp = tid >> 7, j = tid & 127;
        const void* bih = pp ? Gf_bih : Gs_bih;
        const void* bhh = pp ? Gf_bhh : Gs_bhh;
        float br = ld<ISB>(bih, (size_t)t * 384 + j);
        float bz = ld<ISB>(bih, (size_t)t * 384 + 128 + j);
        float bn = ld<ISB>(bih, (size_t)t * 384 + 256 + j);
        float hr = ld<ISB>(bhh, (size_t)t * 384 + j);
        float hz = ld<ISB>(bhh, (size_t)t * 384 + 128 + j);
        float hn = ld<ISB>(bhh, (size_t)t * 384 + 256 + j);
        float* ho = pp ? hf : hs;
        ushortT* hb = pp ? hfb : hsb;
#pragma unroll
        for (int r = 0; r < TN; ++r) {
            int vv = nlist[base + r];
            if (vv < 0) continue;
            float rr = sigm(gi[pp][0][r][j] + br + hr);
            float z = sigm(gi[pp][1][r][j] + bz + hz);
            float n = tanhf(gi[pp][2][r][j] + bn + rr * hn);
            float out = (1.f - z) * n;
            ho[(size_t)vv * D + j] = out;
            hb[(size_t)vv * D + j] = f2b(out);
        }
    }
}

__global__ __launch_bounds__(768) void node_fused(
    const float* agg_s, const float* agg_f, const ushortT* wt,
    const void* Gs_bih, const void* Gs_bhh,
    const void* Gf_bih, const void* Gf_bhh,
    float* hs, float* hf, ushortT* hsb, ushortT* hfb,
    const int* gate, const int* noff, const int* nlist, int level) {
    __shared__ float gi[2][3][16][128];
    if (g_flag)
        node_fused_body<1>(agg_s, agg_f, wt, Gs_bih, Gs_bhh, Gf_bih, Gf_bhh,
                           hs, hf, hsb, hfb, gate, noff, nlist, level, gi);
    else
        node_fused_body<0>(agg_s, agg_f, wt, Gs_bih, Gs_bhh, Gf_bih, Gf_bhh,
                           hs, hf, hsb, hfb, gate, noff, nlist, level, gi);
}

// ---------------- writeout: from f32 canonical ----------------
__global__ void writeout(const float* __restrict__ hs, const float* __restrict__ hf,
                         void* __restrict__ out, int ND) {
    int i = blockIdx.x * blockDim.x + threadIdx.x;
    if (i >= ND) return;
    if (g_flag) {
        ((ushortT*)out)[i] = f2b(hs[i]);
        ((ushortT*)out)[ND + i] = f2b(hf[i]);
    } else {
        ((float*)out)[i] = hs[i];
        ((float*)out)[ND + i] = hf[i];
    }
}

extern "C" void kernel_launch(void* const* d_in, const int* in_sizes, int n_in,
                              void* d_out, int out_size, void* d_ws, size_t ws_size,
                              hipStream_t stream) {
    const void* hs_init = d_in[0];
    const void* Ws1 = d_in[1];
    const void* bs1 = d_in[2];
    const void* Ws2 = d_in[3];
    const void* bs2 = d_in[4];
    const void* Wf1 = d_in[5];
    const void* bf1 = d_in[6];
    const void* Wf2 = d_in[7];
    const void* bf2 = d_in[8];
    const void* Wnf1 = d_in[9];
    const void* bnf1 = d_in[10];
    const void* Wnf2 = d_in[11];
    const void* bnf2 = d_in[12];
    const void* Gs_wih = d_in[13];
    const void* Gs_bih = d_in[15];
    const void* Gs_bhh = d_in[16];
    const void* Gf_wih = d_in[17];
    const void* Gf_bih = d_in[19];
    const void* Gf_bhh = d_in[20];
    const int* edge_index = (const int*)d_in[21];
    const int* gate = (const int*)d_in[22];
    const int* lev = (const int*)d_in[23];

    int E = in_sizes[21] / 2;
    int N = in_sizes[22];
    int ND = N * D;
    int cap = ((N / NLEV + 5 * TN + 64) + TN - 1) / TN * TN;

    float* hs = (float*)d_ws;
    float* hf = hs + ND;
    float* agg_s = hf + ND;
    float* agg_f = agg_s + ND;
    ushortT* hsb = (ushortT*)(agg_f + ND);           // ND ushorts
    ushortT* hfb = hsb + ND;
    ushortT* wt = hfb + ND;                          // WT_TOTAL ushorts
    int* meta = (int*)(wt + WT_TOTAL);
    int* ecnt = meta;            // 20
    int* ncnt = ecnt + 20;       // 20
    int* ncur = ncnt + 20;       // 20
    int* eoff = ncur + 20;       // 21
    int* noff = eoff + 21;       // 21  (meta total 102; pad to 128)
    int* ndeg = meta + 128;      // N
    int* ecur_n = ndeg + N;      // N
    int* nodeoff = ecur_n + N;   // N
    int* elist = nodeoff + N;    // E + 20*TE
    int* nlist = elist + (E + 20 * TE);  // N + 20*TN

    const int* srcA = edge_index;
    const int* dstA = edge_index + E;

    detect_dtype<<<1, 64, 0, stream>>>(hs_init);
    hipMemsetAsync(agg_s, 0, (size_t)2 * ND * sizeof(float), stream);
    hipMemsetAsync(meta, 0, (size_t)(128 + 2 * N) * sizeof(int), stream);  // meta+ndeg+ecur_n
    hipMemsetAsync(elist, 0xFF, (size_t)(E + 20 * TE + N + 20 * TN) * sizeof(int), stream);
    init_state<<<N, D, 0, stream>>>(hs_init, gate, hs, hf, hsb, hfb);

    prep_weights<<<(WT_TOTAL + 255) / 256, 256, 0, stream>>>(
        Ws1, Ws2, Wf1, Wf2, Wnf1, Wnf2, Gs_wih, Gf_wih, wt);

    int mx = (E > N) ? E : N;
    count_bins<<<(mx + 255) / 256, 256, 0, stream>>>(dstA, gate, lev, E, N, ecnt, ncnt, ndeg);
    scan_offsets<<<1, 64, 0, stream>>>(ecnt, ncnt, eoff, noff);
    fill_bins<<<(N + 255) / 256, 256, 0, stream>>>(gate, lev, N, noff, ncur, nlist);
    bucket_scan<<<20, 256, 0, stream>>>(nlist, noff, ncnt, eoff, ndeg, nodeoff);
    fill_edges<<<(E + 255) / 256, 256, 0, stream>>>(dstA, lev, E, nodeoff, ecur_n, elist);

    int gridE = (E + 20 * TE) / TE + 1;
    int gridNcap = cap / TN;
    for (int level = 1; level < NLEV; ++level) {
        edge_mfma<<<gridE, 256, 0, stream>>>(hsb, hfb, wt,
                                             bs1, bs2, bf1, bf2, bnf1, bnf2,
                                             dstA, srcA, gate, eoff, elist,
                                             agg_s, agg_f, level);
        node_fused<<<gridNcap, 768, 0, stream>>>(agg_s, agg_f, wt,
                                                 Gs_bih, Gs_bhh, Gf_bih, Gf_bhh,
                                                 hs, hf, hsb, hfb,
                                                 gate, noff, nlist, level);
    }

    writeout<<<(ND + 255) / 256, 256, 0, stream>>>(hs, hf, d_out, ND);
}